// Round 2
// baseline (467.657 us; speedup 1.0000x reference)
//
#include <hip/hip_runtime.h>
#include <cstdint>
#include <cstddef>

// ---------------- problem constants ----------------
#define NHEADS 16
#define HDIM   64
#define SEQ    2048
#define BATCH  4
#define IND    1024
#define MTOT   (BATCH*SEQ)   // 8192

typedef __attribute__((ext_vector_type(8))) short bf16x8;
typedef __attribute__((ext_vector_type(4))) float f32x4;

__device__ __forceinline__ unsigned short f2b(float f) {
  unsigned u = __builtin_bit_cast(unsigned, f);
  u += 0x7FFFu + ((u >> 16) & 1u);
  return (unsigned short)(u >> 16);
}
__device__ __forceinline__ float b2f(unsigned short b) {
  unsigned u = ((unsigned)b) << 16;
  return __builtin_bit_cast(float, u);
}

__device__ __forceinline__ void gload_lds16(const void* g, void* l) {
  __builtin_amdgcn_global_load_lds(
      (const __attribute__((address_space(1))) void*)g,
      (__attribute__((address_space(3))) void*)l, 16, 0, 0);
}

// ---------------- fp32 -> bf16 conversion ----------------
__global__ void cvt_kernel(const float* __restrict__ src,
                           unsigned short* __restrict__ dst, int n4) {
  int i = blockIdx.x * blockDim.x + threadIdx.x;
  const int stride = gridDim.x * blockDim.x;
  for (; i < n4; i += stride) {
    const float4 v = reinterpret_cast<const float4*>(src)[i];
    ushort4 o;
    o.x = f2b(v.x); o.y = f2b(v.y); o.z = f2b(v.z); o.w = f2b(v.w);
    reinterpret_cast<ushort4*>(dst)[i] = o;
  }
}

// ---------------- GEMM core: C[m,n] = sum_k A[m,k]*B[n,k]  (both row-major, K contig) ----------------
// 128x128 tile, BK=32, 4 waves, each wave 64x64 (4x4 of 16x16), mfma_f32_16x16x32_bf16.
// EPI==0: bf16 out scattered to [B,H,S,64] head layout, value = (acc+bias)*scale
// EPI==2: bf16 out scattered to [B,H,64,S] (transposed head layout), value = acc+bias
// EPI==1: f32 out row-major [M,1024], value = acc+bias
template<int EPI>
__device__ __forceinline__ void gemm_core(
    const unsigned short* __restrict__ A,
    const unsigned short* __restrict__ Bw,
    const float* __restrict__ bias,
    void* __restrict__ Cout, float scale)
{
  __shared__ alignas(16) unsigned short As[2][4096];
  __shared__ alignas(16) unsigned short Bs[2][4096];
  const int tid = threadIdx.x;
  const int wv = tid >> 6, lane = tid & 63, g = lane >> 4, li = lane & 15;
  const int wr = (wv >> 1) * 64, wc = (wv & 1) * 64;
  const int m0 = blockIdx.x * 128, n0 = blockIdx.y * 128;

  auto stage = [&](int buf, int kt) {
    const int k0 = kt * 32;
#pragma unroll
    for (int rnd = 0; rnd < 2; ++rnd) {
      const int f = (tid + rnd * 256) * 8;
      const int row = f >> 5, col = f & 31;
      gload_lds16(&A[(size_t)(m0 + row) * IND + k0 + col], &As[buf][f]);
      gload_lds16(&Bw[(size_t)(n0 + row) * IND + k0 + col], &Bs[buf][f]);
    }
  };

  f32x4 acc[4][4] = {};
  stage(0, 0);
  for (int kt = 0; kt < 32; ++kt) {
    __syncthreads();                 // tile kt staged (vmcnt drained by barrier)
    if (kt + 1 < 32) stage((kt + 1) & 1, kt + 1);  // prefetch overlaps compute
    const int buf = kt & 1;
    bf16x8 af[4], bfr[4];
#pragma unroll
    for (int i = 0; i < 4; ++i)
      af[i] = *(const bf16x8*)&As[buf][(wr + i * 16 + li) * 32 + g * 8];
#pragma unroll
    for (int i = 0; i < 4; ++i)
      bfr[i] = *(const bf16x8*)&Bs[buf][(wc + i * 16 + li) * 32 + g * 8];
#pragma unroll
    for (int mi = 0; mi < 4; ++mi)
#pragma unroll
      for (int ni = 0; ni < 4; ++ni)
        acc[mi][ni] = __builtin_amdgcn_mfma_f32_16x16x32_bf16(
            af[mi], bfr[ni], acc[mi][ni], 0, 0, 0);
  }

#pragma unroll
  for (int ni = 0; ni < 4; ++ni) {
    const int col = n0 + wc + ni * 16 + li;     // n index
    const float bz = bias[col];
#pragma unroll
    for (int mi = 0; mi < 4; ++mi) {
#pragma unroll
      for (int r = 0; r < 4; ++r) {
        const int row = m0 + wr + mi * 16 + g * 4 + r;   // m index
        float v = acc[mi][ni][r] + bz;
        if (EPI == 0) {
          v *= scale;
          const int h = col >> 6, d = col & 63;
          const int b = row >> 11, s = row & 2047;
          ((unsigned short*)Cout)[(((size_t)(b * NHEADS + h)) * SEQ + s) * HDIM + d] = f2b(v);
        } else if (EPI == 2) {
          const int h = col >> 6, d = col & 63;
          const int b = row >> 11, s = row & 2047;
          ((unsigned short*)Cout)[(((size_t)(b * NHEADS + h)) * HDIM + d) * SEQ + s] = f2b(v);
        } else {
          ((float*)Cout)[(size_t)row * IND + col] = v;
        }
      }
    }
  }
}

__global__ __launch_bounds__(256, 2)
void gemm_qkv_kernel(const unsigned short* __restrict__ xb,
                     const unsigned short* __restrict__ Wq,
                     const unsigned short* __restrict__ Wk,
                     const unsigned short* __restrict__ Wv,
                     const float* __restrict__ bq,
                     const float* __restrict__ bk,
                     const float* __restrict__ bv,
                     unsigned short* __restrict__ Qo,
                     unsigned short* __restrict__ Ko,
                     unsigned short* __restrict__ Vto)
{
  const int z = blockIdx.z;
  if (z == 2) {
    // V: write TRANSPOSED head layout [B,H,64,S] so attention reads V columns
    // with the same linear staging pattern as K.
    gemm_core<2>(xb, Wv, bv, Vto, 1.0f);
  } else {
    const unsigned short* Bw = (z == 0) ? Wq : Wk;
    const float* bias = (z == 0) ? bq : bk;
    unsigned short* out = (z == 0) ? Qo : Ko;
    const float scale = (z == 0) ? 0.125f : 1.0f;   // fold 1/sqrt(64) into Q
    gemm_core<0>(xb, Bw, bias, out, scale);
  }
}

__global__ __launch_bounds__(256, 2)
void gemm_o_kernel(const unsigned short* __restrict__ Ab,
                   const unsigned short* __restrict__ Wo,
                   const float* __restrict__ bo,
                   float* __restrict__ out)
{
  gemm_core<1>(Ab, Wo, bo, out, 1.0f);
}

// ---------------- flash attention ----------------
// grid: (SEQ/64, BATCH*NHEADS), 256 threads = 4 waves, wave owns 16 Q rows.
// Q,K in [B,H,S,64] bf16; Vt in [B,H,64,S] bf16. KV tiles of 32 keys, double-buffered LDS.
// K staged linear [32 key][64 d]; Vt staged linear [64 d][32 key].
__global__ __launch_bounds__(256, 2)
void attn_kernel(const unsigned short* __restrict__ Q,
                 const unsigned short* __restrict__ K,
                 const unsigned short* __restrict__ Vt,
                 unsigned short* __restrict__ O)
{
  __shared__ alignas(16) unsigned short Kb[2][32 * 64];
  __shared__ alignas(16) unsigned short Vb[2][64 * 32];
  __shared__ alignas(16) unsigned short Pl[4][16][40];   // [wave][q][key] pad 32->40

  const int tid = threadIdx.x;
  const int wv = tid >> 6, lane = tid & 63, g = lane >> 4, li = lane & 15;
  const int bh = blockIdx.y;
  const size_t hbase = (size_t)bh * (SEQ * HDIM);
  const unsigned short* Qh = Q + hbase;
  const unsigned short* Kh = K + hbase;
  const unsigned short* Vh = Vt + hbase;   // [64][2048]
  const int q0 = blockIdx.x * 64 + wv * 16;

  // Q fragments held in registers for the whole kernel (A-frag: row=li, k=g*8+j)
  const bf16x8 qf0 = *(const bf16x8*)&Qh[(size_t)(q0 + li) * HDIM + g * 8];
  const bf16x8 qf1 = *(const bf16x8*)&Qh[(size_t)(q0 + li) * HDIM + 32 + g * 8];

  f32x4 accO[4] = {};
  float m_r[4], l_r[4];
#pragma unroll
  for (int r = 0; r < 4; ++r) { m_r[r] = -INFINITY; l_r[r] = 0.0f; }

  auto stage = [&](int buf, int kv) {
    const int k0 = kv * 32;
    {   // K: linear [key][d]
      const int f = tid * 8;
      const int row = f >> 6, c = f & 63;
      gload_lds16(&Kh[(size_t)(k0 + row) * HDIM + c], &Kb[buf][f]);
    }
    {   // Vt: linear [d][key], rows stride SEQ in global
      const int f = tid * 8;
      const int row = f >> 5, c = f & 31;
      gload_lds16(&Vh[(size_t)row * SEQ + k0 + c], &Vb[buf][f]);
    }
  };

  stage(0, 0);
  const float L2E = 1.4426950408889634f;

  for (int kv = 0; kv < 64; ++kv) {
    __syncthreads();                       // tile kv resident
    if (kv + 1 < 64) stage((kv + 1) & 1, kv + 1);
    const int buf = kv & 1;

    // ---- QK^T : S[16q, 32keys] in two C-frags (row=q=g*4+r, col=key=li) ----
    f32x4 s0 = {0.f, 0.f, 0.f, 0.f}, s1 = {0.f, 0.f, 0.f, 0.f};
    {
      const bf16x8 kb0 = *(const bf16x8*)&Kb[buf][(li) * 64 + g * 8];
      const bf16x8 kb1 = *(const bf16x8*)&Kb[buf][(li) * 64 + 32 + g * 8];
      s0 = __builtin_amdgcn_mfma_f32_16x16x32_bf16(qf0, kb0, s0, 0, 0, 0);
      s0 = __builtin_amdgcn_mfma_f32_16x16x32_bf16(qf1, kb1, s0, 0, 0, 0);
      const bf16x8 kb2 = *(const bf16x8*)&Kb[buf][(16 + li) * 64 + g * 8];
      const bf16x8 kb3 = *(const bf16x8*)&Kb[buf][(16 + li) * 64 + 32 + g * 8];
      s1 = __builtin_amdgcn_mfma_f32_16x16x32_bf16(qf0, kb2, s1, 0, 0, 0);
      s1 = __builtin_amdgcn_mfma_f32_16x16x32_bf16(qf1, kb3, s1, 0, 0, 0);
    }

    // ---- online softmax (rows g*4+r; reduce over keys = 16-lane butterfly + 2 frags) ----
#pragma unroll
    for (int r = 0; r < 4; ++r) {
      float a = fmaxf(s0[r], s1[r]);
      a = fmaxf(a, __shfl_xor(a, 1));
      a = fmaxf(a, __shfl_xor(a, 2));
      a = fmaxf(a, __shfl_xor(a, 4));
      a = fmaxf(a, __shfl_xor(a, 8));
      const float mn = fmaxf(m_r[r], a);
      const float al = exp2f((m_r[r] - mn) * L2E);
      const float e0 = exp2f((s0[r] - mn) * L2E);
      const float e1 = exp2f((s1[r] - mn) * L2E);
      const unsigned short pb0 = f2b(e0), pb1 = f2b(e1);
      float rs = b2f(pb0) + b2f(pb1);       // sum the *rounded* P so l matches PV exactly
      rs += __shfl_xor(rs, 1);
      rs += __shfl_xor(rs, 2);
      rs += __shfl_xor(rs, 4);
      rs += __shfl_xor(rs, 8);
      l_r[r] = l_r[r] * al + rs;
      m_r[r] = mn;
      accO[0][r] *= al; accO[1][r] *= al; accO[2][r] *= al; accO[3][r] *= al;
      Pl[wv][g * 4 + r][li] = pb0;
      Pl[wv][g * 4 + r][li + 16] = pb1;
    }

    // ---- P A-frag (row=q=li, k=key=g*8+j) via per-wave LDS transpose ----
    const bf16x8 pa = *(const bf16x8*)&Pl[wv][li][g * 8];

    // ---- V B-frags: lane holds Vt[d=t*16+li][key=g*8+j] = V[key][d], contiguous b128 ----
#pragma unroll
    for (int t = 0; t < 4; ++t) {
      const bf16x8 vf = *(const bf16x8*)&Vb[buf][(t * 16 + li) * 32 + g * 8];
      accO[t] = __builtin_amdgcn_mfma_f32_16x16x32_bf16(pa, vf, accO[t], 0, 0, 0);
    }
  }

  // ---- epilogue: O / l, write to [B, S, H*64] ----
  const int b = bh >> 4, h = bh & 15;
#pragma unroll
  for (int r = 0; r < 4; ++r) {
    const float inv = 1.0f / l_r[r];
    const int qrow = blockIdx.x * 64 + wv * 16 + g * 4 + r;
    const size_t base = ((size_t)(b * SEQ + qrow)) * IND + h * HDIM + li;
#pragma unroll
    for (int t = 0; t < 4; ++t)
      O[base + t * 16] = f2b(accO[t][r] * inv);
  }
}

// ---------------- launch ----------------
extern "C" void kernel_launch(void* const* d_in, const int* in_sizes, int n_in,
                              void* d_out, int out_size, void* d_ws, size_t ws_size,
                              hipStream_t stream) {
  const float* x  = (const float*)d_in[0];
  const float* Wq = (const float*)d_in[1];
  const float* bq = (const float*)d_in[2];
  const float* Wk = (const float*)d_in[3];
  const float* bk = (const float*)d_in[4];
  const float* Wv = (const float*)d_in[5];
  const float* bv = (const float*)d_in[6];
  const float* Wo = (const float*)d_in[7];
  const float* bo = (const float*)d_in[8];

  char* ws = (char*)d_ws;
  constexpr size_t SZ_XB = (size_t)MTOT * IND * 2;   // 16 MB
  constexpr size_t SZ_W  = (size_t)IND * IND * 2;    // 2 MB
  unsigned short* xb   = (unsigned short*)(ws);
  unsigned short* Wqb  = (unsigned short*)(ws + SZ_XB);
  unsigned short* Wkb  = (unsigned short*)(ws + SZ_XB + SZ_W);
  unsigned short* Wvb  = (unsigned short*)(ws + SZ_XB + 2 * SZ_W);
  unsigned short* Wob  = (unsigned short*)(ws + SZ_XB + 3 * SZ_W);
  unsigned short* Qb   = (unsigned short*)(ws + SZ_XB + 4 * SZ_W);
  unsigned short* Kbuf = (unsigned short*)(ws + 2 * SZ_XB + 4 * SZ_W);
  unsigned short* Vtb  = (unsigned short*)(ws + 3 * SZ_XB + 4 * SZ_W);
  unsigned short* AOb  = (unsigned short*)(ws + 4 * SZ_XB + 4 * SZ_W);

  // fp32 -> bf16
  cvt_kernel<<<2048, 256, 0, stream>>>(x, xb, (MTOT * IND) / 4);
  cvt_kernel<<<512, 256, 0, stream>>>(Wq, Wqb, (IND * IND) / 4);
  cvt_kernel<<<512, 256, 0, stream>>>(Wk, Wkb, (IND * IND) / 4);
  cvt_kernel<<<512, 256, 0, stream>>>(Wv, Wvb, (IND * IND) / 4);
  cvt_kernel<<<512, 256, 0, stream>>>(Wo, Wob, (IND * IND) / 4);

  // QKV projections (z selects weight); Q pre-scaled by 1/8; V written transposed
  gemm_qkv_kernel<<<dim3(MTOT / 128, IND / 128, 3), 256, 0, stream>>>(
      xb, Wqb, Wkb, Wvb, bq, bk, bv, Qb, Kbuf, Vtb);

  // flash attention
  attn_kernel<<<dim3(SEQ / 64, BATCH * NHEADS), 256, 0, stream>>>(Qb, Kbuf, Vtb, AOb);

  // output projection -> fp32 d_out
  gemm_o_kernel<<<dim3(MTOT / 128, IND / 128), 256, 0, stream>>>(
      AOb, Wob, bo, (float*)d_out);
}

// Round 4
// 253.222 us; speedup vs baseline: 1.8468x; 1.8468x over previous
//
#include <hip/hip_runtime.h>
#include <cstdint>
#include <cstddef>

// ---------------- problem constants ----------------
#define NHEADS 16
#define HDIM   64
#define SEQ    2048
#define BATCH  4
#define IND    1024
#define MTOT   (BATCH*SEQ)   // 8192

typedef __attribute__((ext_vector_type(8))) short bf16x8;
typedef __attribute__((ext_vector_type(4))) float f32x4;
typedef __attribute__((ext_vector_type(16))) float f32x16;

__device__ __forceinline__ unsigned short f2b(float f) {
  unsigned u = __builtin_bit_cast(unsigned, f);
  u += 0x7FFFu + ((u >> 16) & 1u);
  return (unsigned short)(u >> 16);
}
__device__ __forceinline__ float b2f(unsigned short b) {
  unsigned u = ((unsigned)b) << 16;
  return __builtin_bit_cast(float, u);
}
// manual 2xf32 -> packed 2xbf16 (lo in bits 0-15). No pk-instruction semantics risk.
__device__ __forceinline__ unsigned pack2(unsigned short lo, unsigned short hi) {
  return (unsigned)lo | ((unsigned)hi << 16);
}

__device__ __forceinline__ void gload_lds16(const void* g, void* l) {
  __builtin_amdgcn_global_load_lds(
      (const __attribute__((address_space(1))) void*)g,
      (__attribute__((address_space(3))) void*)l, 16, 0, 0);
}

// ---------------- fp32 -> bf16 conversion ----------------
__global__ void cvt_kernel(const float* __restrict__ src,
                           unsigned short* __restrict__ dst, int n4) {
  int i = blockIdx.x * blockDim.x + threadIdx.x;
  const int stride = gridDim.x * blockDim.x;
  for (; i < n4; i += stride) {
    const float4 v = reinterpret_cast<const float4*>(src)[i];
    ushort4 o;
    o.x = f2b(v.x); o.y = f2b(v.y); o.z = f2b(v.z); o.w = f2b(v.w);
    reinterpret_cast<ushort4*>(dst)[i] = o;
  }
}

// ---------------- GEMM core: C[m,n] = sum_k A[m,k]*B[n,k] ----------------
// (unchanged from passing round-2 kernel)
template<int EPI>
__device__ __forceinline__ void gemm_core(
    const unsigned short* __restrict__ A,
    const unsigned short* __restrict__ Bw,
    const float* __restrict__ bias,
    void* __restrict__ Cout, float scale)
{
  __shared__ alignas(16) unsigned short As[2][4096];
  __shared__ alignas(16) unsigned short Bs[2][4096];
  const int tid = threadIdx.x;
  const int wv = tid >> 6, lane = tid & 63, g = lane >> 4, li = lane & 15;
  const int wr = (wv >> 1) * 64, wc = (wv & 1) * 64;
  const int m0 = blockIdx.x * 128, n0 = blockIdx.y * 128;

  auto stage = [&](int buf, int kt) {
    const int k0 = kt * 32;
#pragma unroll
    for (int rnd = 0; rnd < 2; ++rnd) {
      const int f = (tid + rnd * 256) * 8;
      const int row = f >> 5, col = f & 31;
      gload_lds16(&A[(size_t)(m0 + row) * IND + k0 + col], &As[buf][f]);
      gload_lds16(&Bw[(size_t)(n0 + row) * IND + k0 + col], &Bs[buf][f]);
    }
  };

  f32x4 acc[4][4] = {};
  stage(0, 0);
  for (int kt = 0; kt < 32; ++kt) {
    __syncthreads();
    if (kt + 1 < 32) stage((kt + 1) & 1, kt + 1);
    const int buf = kt & 1;
    bf16x8 af[4], bfr[4];
#pragma unroll
    for (int i = 0; i < 4; ++i)
      af[i] = *(const bf16x8*)&As[buf][(wr + i * 16 + li) * 32 + g * 8];
#pragma unroll
    for (int i = 0; i < 4; ++i)
      bfr[i] = *(const bf16x8*)&Bs[buf][(wc + i * 16 + li) * 32 + g * 8];
#pragma unroll
    for (int mi = 0; mi < 4; ++mi)
#pragma unroll
      for (int ni = 0; ni < 4; ++ni)
        acc[mi][ni] = __builtin_amdgcn_mfma_f32_16x16x32_bf16(
            af[mi], bfr[ni], acc[mi][ni], 0, 0, 0);
  }

#pragma unroll
  for (int ni = 0; ni < 4; ++ni) {
    const int col = n0 + wc + ni * 16 + li;
    const float bz = bias[col];
#pragma unroll
    for (int mi = 0; mi < 4; ++mi) {
#pragma unroll
      for (int r = 0; r < 4; ++r) {
        const int row = m0 + wr + mi * 16 + g * 4 + r;
        float v = acc[mi][ni][r] + bz;
        if (EPI == 0) {
          v *= scale;
          const int h = col >> 6, d = col & 63;
          const int b = row >> 11, s = row & 2047;
          ((unsigned short*)Cout)[(((size_t)(b * NHEADS + h)) * SEQ + s) * HDIM + d] = f2b(v);
        } else if (EPI == 2) {
          const int h = col >> 6, d = col & 63;
          const int b = row >> 11, s = row & 2047;
          ((unsigned short*)Cout)[(((size_t)(b * NHEADS + h)) * HDIM + d) * SEQ + s] = f2b(v);
        } else {
          ((float*)Cout)[(size_t)row * IND + col] = v;
        }
      }
    }
  }
}

__global__ __launch_bounds__(256, 2)
void gemm_qkv_kernel(const unsigned short* __restrict__ xb,
                     const unsigned short* __restrict__ Wq,
                     const unsigned short* __restrict__ Wk,
                     const unsigned short* __restrict__ Wv,
                     const float* __restrict__ bq,
                     const float* __restrict__ bk,
                     const float* __restrict__ bv,
                     unsigned short* __restrict__ Qo,
                     unsigned short* __restrict__ Ko,
                     unsigned short* __restrict__ Vto)
{
  const int z = blockIdx.z;
  if (z == 2) {
    gemm_core<2>(xb, Wv, bv, Vto, 1.0f);    // V transposed: [B,H,64,S]
  } else {
    const unsigned short* Bw = (z == 0) ? Wq : Wk;
    const float* bias = (z == 0) ? bq : bk;
    unsigned short* out = (z == 0) ? Qo : Ko;
    const float scale = (z == 0) ? 0.125f : 1.0f;   // fold 1/sqrt(64) into Q
    gemm_core<0>(xb, Bw, bias, out, scale);
  }
}

__global__ __launch_bounds__(256, 2)
void gemm_o_kernel(const unsigned short* __restrict__ Ab,
                   const unsigned short* __restrict__ Wo,
                   const float* __restrict__ bo,
                   float* __restrict__ out)
{
  gemm_core<1>(Ab, Wo, bo, out, 1.0f);
}

// ---------------- flash attention: 8 waves x 32 q, 32x32x16 MFMA, swapped QK^T ----------------
// grid (SEQ/256, B*H), 512 threads. KV tile = 32 keys, double-buffered.
// K LDS [32 key][64 d] chunk-swizzled ch^=(row&7); Vt LDS [64 d][32 key] ch^=((row>>1)&3).
// Swapped QK^T (A=K, B=Q): C col=lane&31 = q -> scores lane-local per q.
// PV (A=Vt, B=P): C col=lane&31 = q -> O^T frags, same lane owns same q.
__global__ __launch_bounds__(512, 4)
void attn_kernel(const unsigned short* __restrict__ Q,
                 const unsigned short* __restrict__ K,
                 const unsigned short* __restrict__ Vt,
                 unsigned short* __restrict__ O)
{
  __shared__ alignas(16) unsigned short Kb[2][32 * 64];   // 8 KB
  __shared__ alignas(16) unsigned short Vb[2][64 * 32];   // 8 KB
  __shared__ alignas(16) unsigned short Pl[8][32][40];    // 20 KB, stride 80B (16B-mult)

  const int tid = threadIdx.x;
  const int wv = tid >> 6, lane = tid & 63;
  const int r31 = lane & 31, hi = lane >> 5;
  const int bh = blockIdx.y;
  const size_t hbase = (size_t)bh * (SEQ * HDIM);
  const unsigned short* Qh = Q + hbase;
  const unsigned short* Kh = K + hbase;
  const unsigned short* Vh = Vt + hbase;   // [64][2048]
  const int q0 = blockIdx.x * 256 + wv * 32;

  // Q B-frags (row=lane&31=q, k=kc*16+hi*8+j), kept in registers all kernel
  bf16x8 qf[4];
#pragma unroll
  for (int kc = 0; kc < 4; ++kc)
    qf[kc] = *(const bf16x8*)&Qh[(size_t)(q0 + r31) * HDIM + kc * 16 + hi * 8];

  f32x16 accO[2] = {};
  float m_run = -INFINITY, l_run = 0.0f;
  const float L2E = 1.4426950408889634f;

  auto stage = [&](int buf, int kv) {
    const int k0 = kv * 32;
    if (tid < 256) {                       // K tile: 4KB = 256 x 16B
      const int row = tid >> 3, pch = tid & 7;
      const int ch = pch ^ (row & 7);      // pre-swizzled source chunk
      gload_lds16(&Kh[(size_t)(k0 + row) * HDIM + ch * 8], &Kb[buf][tid * 8]);
    } else {                               // V tile: 4KB
      const int t = tid - 256;
      const int row = t >> 2, pch = t & 3; // row = d
      const int ch = pch ^ ((row >> 1) & 3);
      gload_lds16(&Vh[(size_t)row * SEQ + k0 + ch * 8], &Vb[buf][t * 8]);
    }
  };

  stage(0, 0);

  for (int kv = 0; kv < SEQ / 32; ++kv) {
    __syncthreads();                       // tile kv resident (barrier drains vmcnt)
    if (kv + 1 < SEQ / 32) stage((kv + 1) & 1, kv + 1);
    const int buf = kv & 1;

    // ---- QK^T: one 32x32 C-frag; scores s[r] = S[key=(r&3)+8*(r>>2)+4hi][q=r31] ----
    f32x16 s = {};
#pragma unroll
    for (int kc = 0; kc < 4; ++kc) {
      const int pch = (kc * 2 + hi) ^ (r31 & 7);
      const bf16x8 kf = *(const bf16x8*)&Kb[buf][r31 * 64 + pch * 8];
      s = __builtin_amdgcn_mfma_f32_32x32x16_bf16(kf, qf[kc], s, 0, 0, 0);
    }

    // ---- tile max (in-register tree + one cross-half shuffle) ----
    float p01 = fmaxf(s[0], s[1]),  p23 = fmaxf(s[2], s[3]);
    float p45 = fmaxf(s[4], s[5]),  p67 = fmaxf(s[6], s[7]);
    float p89 = fmaxf(s[8], s[9]),  pab = fmaxf(s[10], s[11]);
    float pcd = fmaxf(s[12], s[13]), pef = fmaxf(s[14], s[15]);
    float pmax = fmaxf(fmaxf(fmaxf(p01, p23), fmaxf(p45, p67)),
                       fmaxf(fmaxf(p89, pab), fmaxf(pcd, pef)));
    pmax = fmaxf(pmax, __shfl_xor(pmax, 32));

    // ---- defer-max (T13): rescale only when tile max jumps by > 8 ----
    if (!__all(pmax - m_run <= 8.0f)) {
      const float mn = fmaxf(m_run, pmax);
      const float al = exp2f((m_run - mn) * L2E);
      l_run *= al;
#pragma unroll
      for (int f = 0; f < 2; ++f)
#pragma unroll
        for (int r = 0; r < 16; ++r) accO[f][r] *= al;
      m_run = mn;
    }
    const float nmk = -(m_run * L2E);

    // ---- exp + round to bf16 + store P rows (lane owns q=r31); l sums ROUNDED P ----
    float rs = 0.0f;
#pragma unroll
    for (int half = 0; half < 4; ++half) {
      const float e0 = exp2f(fmaf(s[half * 4 + 0], L2E, nmk));
      const float e1 = exp2f(fmaf(s[half * 4 + 1], L2E, nmk));
      const float e2 = exp2f(fmaf(s[half * 4 + 2], L2E, nmk));
      const float e3 = exp2f(fmaf(s[half * 4 + 3], L2E, nmk));
      const unsigned short b0 = f2b(e0), b1 = f2b(e1), b2 = f2b(e2), b3 = f2b(e3);
      rs += (b2f(b0) + b2f(b1)) + (b2f(b2) + b2f(b3));
      uint2 w; w.x = pack2(b0, b1); w.y = pack2(b2, b3);
      // keys 8*half + 4*hi + {0..3} for row q=r31
      *(uint2*)&Pl[wv][r31][half * 8 + hi * 4] = w;
    }
    rs += __shfl_xor(rs, 32);
    l_run += rs;

    // ---- PV: O^T[d][q] += Vt[d][k] * P[q][k] ----
#pragma unroll
    for (int kc2 = 0; kc2 < 2; ++kc2) {
      const bf16x8 pf = *(const bf16x8*)&Pl[wv][r31][kc2 * 16 + hi * 8];
#pragma unroll
      for (int f = 0; f < 2; ++f) {
        const int row = 32 * f + r31;      // d
        const int pch = (kc2 * 2 + hi) ^ ((r31 >> 1) & 3);
        const bf16x8 vf = *(const bf16x8*)&Vb[buf][row * 32 + pch * 8];
        accO[f] = __builtin_amdgcn_mfma_f32_32x32x16_bf16(vf, pf, accO[f], 0, 0, 0);
      }
    }
  }

  // ---- epilogue: O[q][d] = accO^T / l, write bf16 to [B, S, H*64] ----
  const int b = bh >> 4, h = bh & 15;
  const float inv = 1.0f / l_run;
  const int qrow = q0 + r31;
  unsigned short* obase = (unsigned short*)&O[((size_t)(b * SEQ + qrow)) * IND + h * HDIM];
#pragma unroll
  for (int f = 0; f < 2; ++f) {
#pragma unroll
    for (int half = 0; half < 4; ++half) {
      // d = 32f + 8*half + 4*hi + {0..3}  <- regs half*4 + {0..3}
      uint2 w;
      w.x = pack2(f2b(accO[f][half * 4 + 0] * inv), f2b(accO[f][half * 4 + 1] * inv));
      w.y = pack2(f2b(accO[f][half * 4 + 2] * inv), f2b(accO[f][half * 4 + 3] * inv));
      *(uint2*)&obase[32 * f + 8 * half + 4 * hi] = w;
    }
  }
}

// ---------------- launch ----------------
extern "C" void kernel_launch(void* const* d_in, const int* in_sizes, int n_in,
                              void* d_out, int out_size, void* d_ws, size_t ws_size,
                              hipStream_t stream) {
  const float* x  = (const float*)d_in[0];
  const float* Wq = (const float*)d_in[1];
  const float* bq = (const float*)d_in[2];
  const float* Wk = (const float*)d_in[3];
  const float* bk = (const float*)d_in[4];
  const float* Wv = (const float*)d_in[5];
  const float* bv = (const float*)d_in[6];
  const float* Wo = (const float*)d_in[7];
  const float* bo = (const float*)d_in[8];

  char* ws = (char*)d_ws;
  constexpr size_t SZ_XB = (size_t)MTOT * IND * 2;   // 16 MB
  constexpr size_t SZ_W  = (size_t)IND * IND * 2;    // 2 MB
  unsigned short* xb   = (unsigned short*)(ws);
  unsigned short* Wqb  = (unsigned short*)(ws + SZ_XB);
  unsigned short* Wkb  = (unsigned short*)(ws + SZ_XB + SZ_W);
  unsigned short* Wvb  = (unsigned short*)(ws + SZ_XB + 2 * SZ_W);
  unsigned short* Wob  = (unsigned short*)(ws + SZ_XB + 3 * SZ_W);
  unsigned short* Qb   = (unsigned short*)(ws + SZ_XB + 4 * SZ_W);
  unsigned short* Kbuf = (unsigned short*)(ws + 2 * SZ_XB + 4 * SZ_W);
  unsigned short* Vtb  = (unsigned short*)(ws + 3 * SZ_XB + 4 * SZ_W);
  unsigned short* AOb  = (unsigned short*)(ws + 4 * SZ_XB + 4 * SZ_W);

  // fp32 -> bf16
  cvt_kernel<<<2048, 256, 0, stream>>>(x, xb, (MTOT * IND) / 4);
  cvt_kernel<<<512, 256, 0, stream>>>(Wq, Wqb, (IND * IND) / 4);
  cvt_kernel<<<512, 256, 0, stream>>>(Wk, Wkb, (IND * IND) / 4);
  cvt_kernel<<<512, 256, 0, stream>>>(Wv, Wvb, (IND * IND) / 4);
  cvt_kernel<<<512, 256, 0, stream>>>(Wo, Wob, (IND * IND) / 4);

  // QKV projections; Q pre-scaled by 1/8; V written transposed [B,H,64,S]
  gemm_qkv_kernel<<<dim3(MTOT / 128, IND / 128, 3), 256, 0, stream>>>(
      xb, Wqb, Wkb, Wvb, bq, bk, bv, Qb, Kbuf, Vtb);

  // flash attention (8 waves x 32 q = 256 q rows per block)
  attn_kernel<<<dim3(SEQ / 256, BATCH * NHEADS), 512, 0, stream>>>(Qb, Kbuf, Vtb, AOb);

  // output projection -> fp32 d_out
  gemm_o_kernel<<<dim3(MTOT / 128, IND / 128), 256, 0, stream>>>(
      AOb, Wob, bo, (float*)d_out);
}

// Round 6
// 245.633 us; speedup vs baseline: 1.9039x; 1.0309x over previous
//
#include <hip/hip_runtime.h>
#include <hip/hip_bf16.h>
#include <cstdint>
#include <cstddef>

// ---------------- problem constants ----------------
#define NHEADS 16
#define HDIM   64
#define SEQ    2048
#define BATCH  4
#define IND    1024
#define MTOT   (BATCH*SEQ)   // 8192

typedef __attribute__((ext_vector_type(8))) short bf16x8;
typedef __attribute__((ext_vector_type(4))) float f32x4;
typedef __attribute__((ext_vector_type(16))) float f32x16;

__device__ __forceinline__ unsigned short f2b(float f) {
  unsigned u = __builtin_bit_cast(unsigned, f);
  u += 0x7FFFu + ((u >> 16) & 1u);
  return (unsigned short)(u >> 16);
}
// packed 2xf32 -> 2xbf16 RNE via toolchain API (lo -> bits 0-15)
__device__ __forceinline__ unsigned cvt2(float lo, float hi) {
  float2 t; t.x = lo; t.y = hi;
  __hip_bfloat162 h = __float22bfloat162_rn(t);
  const unsigned short ulo = __bfloat16_as_ushort(h.x);
  const unsigned short uhi = __bfloat16_as_ushort(h.y);
  return (unsigned)ulo | ((unsigned)uhi << 16);
}
__device__ __forceinline__ float m3(float a, float b, float c) {
  return fmaxf(fmaxf(a, b), c);   // fuses to v_max3_f32
}

__device__ __forceinline__ void gload_lds16(const void* g, void* l) {
  __builtin_amdgcn_global_load_lds(
      (const __attribute__((address_space(1))) void*)g,
      (__attribute__((address_space(3))) void*)l, 16, 0, 0);
}

// ---------------- fp32 -> bf16 conversion ----------------
__global__ void cvt_kernel(const float* __restrict__ src,
                           unsigned short* __restrict__ dst, int n4) {
  int i = blockIdx.x * blockDim.x + threadIdx.x;
  const int stride = gridDim.x * blockDim.x;
  for (; i < n4; i += stride) {
    const float4 v = reinterpret_cast<const float4*>(src)[i];
    ushort4 o;
    o.x = f2b(v.x); o.y = f2b(v.y); o.z = f2b(v.z); o.w = f2b(v.w);
    reinterpret_cast<ushort4*>(dst)[i] = o;
  }
}

// 4 weight tensors in one launch (blockIdx.y selects)
__global__ void cvtw_kernel(const float* __restrict__ w0, const float* __restrict__ w1,
                            const float* __restrict__ w2, const float* __restrict__ w3,
                            unsigned short* __restrict__ o0, unsigned short* __restrict__ o1,
                            unsigned short* __restrict__ o2, unsigned short* __restrict__ o3,
                            int n4) {
  const int z = blockIdx.y;
  const float* src = (z == 0) ? w0 : (z == 1) ? w1 : (z == 2) ? w2 : w3;
  unsigned short* dst = (z == 0) ? o0 : (z == 1) ? o1 : (z == 2) ? o2 : o3;
  int i = blockIdx.x * blockDim.x + threadIdx.x;
  const int stride = gridDim.x * blockDim.x;
  for (; i < n4; i += stride) {
    const float4 v = reinterpret_cast<const float4*>(src)[i];
    ushort4 o;
    o.x = f2b(v.x); o.y = f2b(v.y); o.z = f2b(v.z); o.w = f2b(v.w);
    reinterpret_cast<ushort4*>(dst)[i] = o;
  }
}

// ---------------- GEMM core: C[m,n] = sum_k A[m,k]*B[n,k] ----------------
// (unchanged verified structure)
template<int EPI>
__device__ __forceinline__ void gemm_core(
    const unsigned short* __restrict__ A,
    const unsigned short* __restrict__ Bw,
    const float* __restrict__ bias,
    void* __restrict__ Cout, float scale)
{
  __shared__ alignas(16) unsigned short As[2][4096];
  __shared__ alignas(16) unsigned short Bs[2][4096];
  const int tid = threadIdx.x;
  const int wv = tid >> 6, lane = tid & 63, g = lane >> 4, li = lane & 15;
  const int wr = (wv >> 1) * 64, wc = (wv & 1) * 64;
  const int m0 = blockIdx.x * 128, n0 = blockIdx.y * 128;

  auto stage = [&](int buf, int kt) {
    const int k0 = kt * 32;
#pragma unroll
    for (int rnd = 0; rnd < 2; ++rnd) {
      const int f = (tid + rnd * 256) * 8;
      const int row = f >> 5, col = f & 31;
      gload_lds16(&A[(size_t)(m0 + row) * IND + k0 + col], &As[buf][f]);
      gload_lds16(&Bw[(size_t)(n0 + row) * IND + k0 + col], &Bs[buf][f]);
    }
  };

  f32x4 acc[4][4] = {};
  stage(0, 0);
  for (int kt = 0; kt < 32; ++kt) {
    __syncthreads();
    if (kt + 1 < 32) stage((kt + 1) & 1, kt + 1);
    const int buf = kt & 1;
    bf16x8 af[4], bfr[4];
#pragma unroll
    for (int i = 0; i < 4; ++i)
      af[i] = *(const bf16x8*)&As[buf][(wr + i * 16 + li) * 32 + g * 8];
#pragma unroll
    for (int i = 0; i < 4; ++i)
      bfr[i] = *(const bf16x8*)&Bs[buf][(wc + i * 16 + li) * 32 + g * 8];
#pragma unroll
    for (int mi = 0; mi < 4; ++mi)
#pragma unroll
      for (int ni = 0; ni < 4; ++ni)
        acc[mi][ni] = __builtin_amdgcn_mfma_f32_16x16x32_bf16(
            af[mi], bfr[ni], acc[mi][ni], 0, 0, 0);
  }

#pragma unroll
  for (int ni = 0; ni < 4; ++ni) {
    const int col = n0 + wc + ni * 16 + li;
    const float bz = bias[col];
#pragma unroll
    for (int mi = 0; mi < 4; ++mi) {
#pragma unroll
      for (int r = 0; r < 4; ++r) {
        const int row = m0 + wr + mi * 16 + g * 4 + r;
        float v = acc[mi][ni][r] + bz;
        if (EPI == 0) {
          v *= scale;
          const int h = col >> 6, d = col & 63;
          const int b = row >> 11, s = row & 2047;
          ((unsigned short*)Cout)[(((size_t)(b * NHEADS + h)) * SEQ + s) * HDIM + d] = f2b(v);
        } else if (EPI == 2) {
          const int h = col >> 6, d = col & 63;
          const int b = row >> 11, s = row & 2047;
          ((unsigned short*)Cout)[(((size_t)(b * NHEADS + h)) * HDIM + d) * SEQ + s] = f2b(v);
        } else {
          ((float*)Cout)[(size_t)row * IND + col] = v;
        }
      }
    }
  }
}

__global__ __launch_bounds__(256, 2)
void gemm_qkv_kernel(const unsigned short* __restrict__ xb,
                     const unsigned short* __restrict__ Wq,
                     const unsigned short* __restrict__ Wk,
                     const unsigned short* __restrict__ Wv,
                     const float* __restrict__ bq,
                     const float* __restrict__ bk,
                     const float* __restrict__ bv,
                     unsigned short* __restrict__ Qo,
                     unsigned short* __restrict__ Ko,
                     unsigned short* __restrict__ Vto)
{
  const int z = blockIdx.z;
  if (z == 2) {
    gemm_core<2>(xb, Wv, bv, Vto, 1.0f);    // V transposed: [B,H,64,S]
  } else {
    const unsigned short* Bw = (z == 0) ? Wq : Wk;
    const float* bias = (z == 0) ? bq : bk;
    unsigned short* out = (z == 0) ? Qo : Ko;
    // Q: fold 1/sqrt(64) AND log2(e) so attention scores are in log2 units
    const float scale = (z == 0) ? 0.18033688011111772f : 1.0f;
    gemm_core<0>(xb, Bw, bias, out, scale);
  }
}

__global__ __launch_bounds__(256, 2)
void gemm_o_kernel(const unsigned short* __restrict__ Ab,
                   const unsigned short* __restrict__ Wo,
                   const float* __restrict__ bo,
                   float* __restrict__ out)
{
  gemm_core<1>(Ab, Wo, bo, out, 1.0f);
}

// ---------------- flash attention: 4 waves x 32 q, KVBLK=64, 32x32x16 MFMA ----------------
// 256 threads; grid flat 1024 = (16 qblk) x (64 bh), XCD-swizzled.
// Scores in log2 units (L2E folded into Q scale).
// K LDS [64 key][64 d], V LDS [64 d][64 key], both chunk-swizzled ch ^= (row&7)
// with pre-swizzled global_load_lds sources (both-sides rule).
__global__ __launch_bounds__(256, 3)
void attn_kernel(const unsigned short* __restrict__ Q,
                 const unsigned short* __restrict__ K,
                 const unsigned short* __restrict__ Vt,
                 unsigned short* __restrict__ O)
{
  __shared__ alignas(16) unsigned short Kb[2][64 * 64];   // 16 KB
  __shared__ alignas(16) unsigned short Vb[2][64 * 64];   // 16 KB
  __shared__ alignas(16) unsigned short Pl[4][32][72];    // 18 KB, row stride 144B

  const int tid = threadIdx.x;
  const int wv = tid >> 6, lane = tid & 63;
  const int r31 = lane & 31, hi = lane >> 5;

  // XCD-aware decode: 1024 blocks, 128 per XCD chunk -> same-head blocks colocate
  const unsigned flat = blockIdx.x;
  const unsigned wg = (flat & 7) * 128 + (flat >> 3);
  const int qblk = wg & 15;
  const int bh = wg >> 4;

  const size_t hbase = (size_t)bh * (SEQ * HDIM);
  const unsigned short* Qh = Q + hbase;
  const unsigned short* Kh = K + hbase;
  const unsigned short* Vh = Vt + hbase;   // [64][2048]
  const int q0 = qblk * 128 + wv * 32;

  // Q B-frags (n=q=r31, k = kc*16 + hi*8 + j); log2-scaled already
  bf16x8 qf[4];
#pragma unroll
  for (int kc = 0; kc < 4; ++kc)
    qf[kc] = *(const bf16x8*)&Qh[(size_t)(q0 + r31) * HDIM + kc * 16 + hi * 8];

  f32x16 accO[2] = {};
  float m_run = -INFINITY, l_run = 0.0f;

  auto stage = [&](int buf, int kv) {
    const int k0 = kv * 64;
#pragma unroll
    for (int rnd = 0; rnd < 2; ++rnd) {
      const int c = tid + rnd * 256;        // 0..511 chunk id
      const int row = c >> 3, pch = c & 7;
      const int ch = pch ^ (row & 7);       // pre-swizzled source chunk
      gload_lds16(&Kh[(size_t)(k0 + row) * HDIM + ch * 8], &Kb[buf][c * 8]);
      gload_lds16(&Vh[(size_t)row * SEQ + k0 + ch * 8], &Vb[buf][c * 8]);
    }
  };

  stage(0, 0);

  for (int kv = 0; kv < SEQ / 64; ++kv) {
    __syncthreads();                        // tile kv resident
    if (kv + 1 < SEQ / 64) stage((kv + 1) & 1, kv + 1);
    const int buf = kv & 1;

    // ---- QK^T (A=K, B=Q): s0 = keys 0-31, s1 = keys 32-63; col=q=r31 ----
    f32x16 s0 = {}, s1 = {};
#pragma unroll
    for (int kc = 0; kc < 4; ++kc) {
      const int pch = (kc * 2 + hi) ^ (r31 & 7);
      const int base = r31 * 64 + pch * 8;
      const bf16x8 kf0 = *(const bf16x8*)&Kb[buf][base];
      s0 = __builtin_amdgcn_mfma_f32_32x32x16_bf16(kf0, qf[kc], s0, 0, 0, 0);
      const bf16x8 kf1 = *(const bf16x8*)&Kb[buf][base + 2048];
      s1 = __builtin_amdgcn_mfma_f32_32x32x16_bf16(kf1, qf[kc], s1, 0, 0, 0);
    }

    // ---- tile max via max3 trees (log2 units) ----
    float t0 = m3(s0[0], s0[1], s0[2]),   t1 = m3(s0[3], s0[4], s0[5]);
    float t2 = m3(s0[6], s0[7], s0[8]),   t3 = m3(s0[9], s0[10], s0[11]);
    float t4 = m3(s0[12], s0[13], s0[14]);
    float u0 = m3(t0, t1, s0[15]),        u1 = fmaxf(t2, fmaxf(t3, t4));
    float t5 = m3(s1[0], s1[1], s1[2]),   t6 = m3(s1[3], s1[4], s1[5]);
    float t7 = m3(s1[6], s1[7], s1[8]),   t8 = m3(s1[9], s1[10], s1[11]);
    float t9 = m3(s1[12], s1[13], s1[14]);
    float u2 = m3(t5, t6, s1[15]),        u3 = fmaxf(t7, fmaxf(t8, t9));
    float pmax = m3(fmaxf(u0, u1), u2, u3);
    pmax = fmaxf(pmax, __shfl_xor(pmax, 32));

    // ---- defer-max (T13, log2 threshold 8) ----
    if (!__all(pmax - m_run <= 8.0f)) {
      const float mn = fmaxf(m_run, pmax);
      const float al = exp2f(m_run - mn);
      l_run *= al;
#pragma unroll
      for (int f = 0; f < 2; ++f)
#pragma unroll
        for (int r = 0; r < 16; ++r) accO[f][r] *= al;
      m_run = mn;
    }

    // ---- exp2 + packed cvt + P store; l sums the ROUNDED P (from packed bits) ----
    float rs = 0.0f;
    auto dohalf = [&](const f32x16& sv, int f) {
#pragma unroll
      for (int half = 0; half < 4; ++half) {
        const float e0 = exp2f(sv[half * 4 + 0] - m_run);
        const float e1 = exp2f(sv[half * 4 + 1] - m_run);
        const float e2 = exp2f(sv[half * 4 + 2] - m_run);
        const float e3 = exp2f(sv[half * 4 + 3] - m_run);
        uint2 w; w.x = cvt2(e0, e1); w.y = cvt2(e2, e3);
        const float r0 = __builtin_bit_cast(float, w.x << 16);
        const float r1 = __builtin_bit_cast(float, w.x & 0xFFFF0000u);
        const float r2 = __builtin_bit_cast(float, w.y << 16);
        const float r3 = __builtin_bit_cast(float, w.y & 0xFFFF0000u);
        rs += (r0 + r1) + (r2 + r3);
        // keys f*32 + half*8 + hi*4 + {0..3} for q=r31
        *(uint2*)&Pl[wv][r31][f * 32 + half * 8 + hi * 4] = w;
      }
    };
    dohalf(s0, 0);
    dohalf(s1, 1);
    rs += __shfl_xor(rs, 32);
    l_run += rs;

    // ---- PV (A=Vt, B=P): O^T[d][q] ----
#pragma unroll
    for (int kc2 = 0; kc2 < 4; ++kc2) {
      const bf16x8 pf = *(const bf16x8*)&Pl[wv][r31][kc2 * 16 + hi * 8];
      const int pch = (kc2 * 2 + hi) ^ (r31 & 7);
      const int vbase = r31 * 64 + pch * 8;
      const bf16x8 vf0 = *(const bf16x8*)&Vb[buf][vbase];
      accO[0] = __builtin_amdgcn_mfma_f32_32x32x16_bf16(vf0, pf, accO[0], 0, 0, 0);
      const bf16x8 vf1 = *(const bf16x8*)&Vb[buf][vbase + 2048];
      accO[1] = __builtin_amdgcn_mfma_f32_32x32x16_bf16(vf1, pf, accO[1], 0, 0, 0);
    }
  }

  // ---- epilogue: O[q][d] = accO^T / l -> [B, S, H*64] bf16 ----
  const int b = bh >> 4, h = bh & 15;
  const float inv = 1.0f / l_run;
  const int qrow = q0 + r31;
  unsigned short* obase = (unsigned short*)&O[((size_t)(b * SEQ + qrow)) * IND + h * HDIM];
#pragma unroll
  for (int f = 0; f < 2; ++f) {
#pragma unroll
    for (int half = 0; half < 4; ++half) {
      // d = 32f + 8*half + 4*hi + {0..3}
      uint2 w;
      w.x = cvt2(accO[f][half * 4 + 0] * inv, accO[f][half * 4 + 1] * inv);
      w.y = cvt2(accO[f][half * 4 + 2] * inv, accO[f][half * 4 + 3] * inv);
      *(uint2*)&obase[32 * f + 8 * half + 4 * hi] = w;
    }
  }
}

// ---------------- launch ----------------
extern "C" void kernel_launch(void* const* d_in, const int* in_sizes, int n_in,
                              void* d_out, int out_size, void* d_ws, size_t ws_size,
                              hipStream_t stream) {
  const float* x  = (const float*)d_in[0];
  const float* Wq = (const float*)d_in[1];
  const float* bq = (const float*)d_in[2];
  const float* Wk = (const float*)d_in[3];
  const float* bk = (const float*)d_in[4];
  const float* Wv = (const float*)d_in[5];
  const float* bv = (const float*)d_in[6];
  const float* Wo = (const float*)d_in[7];
  const float* bo = (const float*)d_in[8];

  char* ws = (char*)d_ws;
  constexpr size_t SZ_XB = (size_t)MTOT * IND * 2;   // 16 MB
  constexpr size_t SZ_W  = (size_t)IND * IND * 2;    // 2 MB
  unsigned short* xb   = (unsigned short*)(ws);
  unsigned short* Wqb  = (unsigned short*)(ws + SZ_XB);
  unsigned short* Wkb  = (unsigned short*)(ws + SZ_XB + SZ_W);
  unsigned short* Wvb  = (unsigned short*)(ws + SZ_XB + 2 * SZ_W);
  unsigned short* Wob  = (unsigned short*)(ws + SZ_XB + 3 * SZ_W);
  unsigned short* Qb   = (unsigned short*)(ws + SZ_XB + 4 * SZ_W);
  unsigned short* Kbuf = (unsigned short*)(ws + 2 * SZ_XB + 4 * SZ_W);
  unsigned short* Vtb  = (unsigned short*)(ws + 3 * SZ_XB + 4 * SZ_W);
  unsigned short* AOb  = (unsigned short*)(ws + 4 * SZ_XB + 4 * SZ_W);

  // fp32 -> bf16 (x + all four weights in 2 launches)
  cvt_kernel<<<2048, 256, 0, stream>>>(x, xb, (MTOT * IND) / 4);
  cvtw_kernel<<<dim3(512, 4), 256, 0, stream>>>(Wq, Wk, Wv, Wo,
                                                Wqb, Wkb, Wvb, Wob, (IND * IND) / 4);

  // QKV projections; Q pre-scaled by log2e/8; V written transposed [B,H,64,S]
  gemm_qkv_kernel<<<dim3(MTOT / 128, IND / 128, 3), 256, 0, stream>>>(
      xb, Wqb, Wkb, Wvb, bq, bk, bv, Qb, Kbuf, Vtb);

  // flash attention: 1024 flat blocks (16 qblk x 64 bh), XCD-swizzled in-kernel
  attn_kernel<<<dim3(16 * BATCH * NHEADS), 256, 0, stream>>>(Qb, Kbuf, Vtb, AOb);

  // output projection -> fp32 d_out
  gemm_o_kernel<<<dim3(MTOT / 128, IND / 128), 256, 0, stream>>>(
      AOb, Wob, bo, (float*)d_out);
}

// Round 8
// 244.641 us; speedup vs baseline: 1.9116x; 1.0041x over previous
//
#include <hip/hip_runtime.h>
#include <hip/hip_bf16.h>
#include <cstdint>
#include <cstddef>

// ---------------- problem constants ----------------
#define NHEADS 16
#define HDIM   64
#define SEQ    2048
#define BATCH  4
#define IND    1024
#define MTOT   (BATCH*SEQ)   // 8192

typedef __attribute__((ext_vector_type(8))) short bf16x8;
typedef __attribute__((ext_vector_type(4))) float f32x4;
typedef __attribute__((ext_vector_type(16))) float f32x16;

__device__ __forceinline__ unsigned short f2b(float f) {
  unsigned u = __builtin_bit_cast(unsigned, f);
  u += 0x7FFFu + ((u >> 16) & 1u);
  return (unsigned short)(u >> 16);
}
// packed 2xf32 -> 2xbf16 RNE via toolchain API (lo -> bits 0-15)
__device__ __forceinline__ unsigned cvt2(float lo, float hi) {
  float2 t; t.x = lo; t.y = hi;
  __hip_bfloat162 h = __float22bfloat162_rn(t);
  const unsigned short ulo = __bfloat16_as_ushort(h.x);
  const unsigned short uhi = __bfloat16_as_ushort(h.y);
  return (unsigned)ulo | ((unsigned)uhi << 16);
}
__device__ __forceinline__ float m3(float a, float b, float c) {
  return fmaxf(fmaxf(a, b), c);   // fuses to v_max3_f32
}

__device__ __forceinline__ void gload_lds16(const void* g, void* l) {
  __builtin_amdgcn_global_load_lds(
      (const __attribute__((address_space(1))) void*)g,
      (__attribute__((address_space(3))) void*)l, 16, 0, 0);
}

// ---------------- fp32 -> bf16 conversion ----------------
__global__ void cvt_kernel(const float* __restrict__ src,
                           unsigned short* __restrict__ dst, int n4) {
  int i = blockIdx.x * blockDim.x + threadIdx.x;
  const int stride = gridDim.x * blockDim.x;
  for (; i < n4; i += stride) {
    const float4 v = reinterpret_cast<const float4*>(src)[i];
    ushort4 o;
    o.x = f2b(v.x); o.y = f2b(v.y); o.z = f2b(v.z); o.w = f2b(v.w);
    reinterpret_cast<ushort4*>(dst)[i] = o;
  }
}

// 4 weight tensors in one launch (blockIdx.y selects)
__global__ void cvtw_kernel(const float* __restrict__ w0, const float* __restrict__ w1,
                            const float* __restrict__ w2, const float* __restrict__ w3,
                            unsigned short* __restrict__ o0, unsigned short* __restrict__ o1,
                            unsigned short* __restrict__ o2, unsigned short* __restrict__ o3,
                            int n4) {
  const int z = blockIdx.y;
  const float* src = (z == 0) ? w0 : (z == 1) ? w1 : (z == 2) ? w2 : w3;
  unsigned short* dst = (z == 0) ? o0 : (z == 1) ? o1 : (z == 2) ? o2 : o3;
  int i = blockIdx.x * blockDim.x + threadIdx.x;
  const int stride = gridDim.x * blockDim.x;
  for (; i < n4; i += stride) {
    const float4 v = reinterpret_cast<const float4*>(src)[i];
    ushort4 o;
    o.x = f2b(v.x); o.y = f2b(v.y); o.z = f2b(v.z); o.w = f2b(v.w);
    reinterpret_cast<ushort4*>(dst)[i] = o;
  }
}

// ---------------- GEMM core: C[m,n] = sum_k A[m,k]*B[n,k] ----------------
// (unchanged verified structure)
template<int EPI>
__device__ __forceinline__ void gemm_core(
    const unsigned short* __restrict__ A,
    const unsigned short* __restrict__ Bw,
    const float* __restrict__ bias,
    void* __restrict__ Cout, float scale)
{
  __shared__ alignas(16) unsigned short As[2][4096];
  __shared__ alignas(16) unsigned short Bs[2][4096];
  const int tid = threadIdx.x;
  const int wv = tid >> 6, lane = tid & 63, g = lane >> 4, li = lane & 15;
  const int wr = (wv >> 1) * 64, wc = (wv & 1) * 64;
  const int m0 = blockIdx.x * 128, n0 = blockIdx.y * 128;

  auto stage = [&](int buf, int kt) {
    const int k0 = kt * 32;
#pragma unroll
    for (int rnd = 0; rnd < 2; ++rnd) {
      const int f = (tid + rnd * 256) * 8;
      const int row = f >> 5, col = f & 31;
      gload_lds16(&A[(size_t)(m0 + row) * IND + k0 + col], &As[buf][f]);
      gload_lds16(&Bw[(size_t)(n0 + row) * IND + k0 + col], &Bs[buf][f]);
    }
  };

  f32x4 acc[4][4] = {};
  stage(0, 0);
  for (int kt = 0; kt < 32; ++kt) {
    __syncthreads();
    if (kt + 1 < 32) stage((kt + 1) & 1, kt + 1);
    const int buf = kt & 1;
    bf16x8 af[4], bfr[4];
#pragma unroll
    for (int i = 0; i < 4; ++i)
      af[i] = *(const bf16x8*)&As[buf][(wr + i * 16 + li) * 32 + g * 8];
#pragma unroll
    for (int i = 0; i < 4; ++i)
      bfr[i] = *(const bf16x8*)&Bs[buf][(wc + i * 16 + li) * 32 + g * 8];
#pragma unroll
    for (int mi = 0; mi < 4; ++mi)
#pragma unroll
      for (int ni = 0; ni < 4; ++ni)
        acc[mi][ni] = __builtin_amdgcn_mfma_f32_16x16x32_bf16(
            af[mi], bfr[ni], acc[mi][ni], 0, 0, 0);
  }

#pragma unroll
  for (int ni = 0; ni < 4; ++ni) {
    const int col = n0 + wc + ni * 16 + li;
    const float bz = bias[col];
#pragma unroll
    for (int mi = 0; mi < 4; ++mi) {
#pragma unroll
      for (int r = 0; r < 4; ++r) {
        const int row = m0 + wr + mi * 16 + g * 4 + r;
        float v = acc[mi][ni][r] + bz;
        if (EPI == 0) {
          v *= scale;
          const int h = col >> 6, d = col & 63;
          const int b = row >> 11, s = row & 2047;
          ((unsigned short*)Cout)[(((size_t)(b * NHEADS + h)) * SEQ + s) * HDIM + d] = f2b(v);
        } else if (EPI == 2) {
          const int h = col >> 6, d = col & 63;
          const int b = row >> 11, s = row & 2047;
          ((unsigned short*)Cout)[(((size_t)(b * NHEADS + h)) * HDIM + d) * SEQ + s] = f2b(v);
        } else {
          ((float*)Cout)[(size_t)row * IND + col] = v;
        }
      }
    }
  }
}

__global__ __launch_bounds__(256, 2)
void gemm_qkv_kernel(const unsigned short* __restrict__ xb,
                     const unsigned short* __restrict__ Wq,
                     const unsigned short* __restrict__ Wk,
                     const unsigned short* __restrict__ Wv,
                     const float* __restrict__ bq,
                     const float* __restrict__ bk,
                     const float* __restrict__ bv,
                     unsigned short* __restrict__ Qo,
                     unsigned short* __restrict__ Ko,
                     unsigned short* __restrict__ Vto)
{
  const int z = blockIdx.z;
  if (z == 2) {
    gemm_core<2>(xb, Wv, bv, Vto, 1.0f);    // V transposed: [B,H,64,S]
  } else {
    const unsigned short* Bw = (z == 0) ? Wq : Wk;
    const float* bias = (z == 0) ? bq : bk;
    unsigned short* out = (z == 0) ? Qo : Ko;
    // Q: fold 1/sqrt(64) AND log2(e) so attention scores are in log2 units
    const float scale = (z == 0) ? 0.18033688011111772f : 1.0f;
    gemm_core<0>(xb, Bw, bias, out, scale);
  }
}

__global__ __launch_bounds__(256, 2)
void gemm_o_kernel(const unsigned short* __restrict__ Ab,
                   const unsigned short* __restrict__ Wo,
                   const float* __restrict__ bo,
                   float* __restrict__ out)
{
  gemm_core<1>(Ab, Wo, bo, out, 1.0f);
}

// ---------------- flash attention: 4 waves x 32 q, KVBLK=64, 32x32x16 MFMA ----------------
// 256 threads; grid flat 1024 = (16 qblk) x (64 bh), XCD-swizzled.
// Scores in log2 units (L2E folded into Q scale).
// K LDS [64 key][64 d], V LDS [64 d][64 key], both chunk-swizzled ch ^= (row&7)
// with pre-swizzled global_load_lds sources (both-sides rule).
// P LDS: per-wave [32 q][64 key] rows of 128B, 16B-chunk XOR swizzle ch ^= (q&7)
// applied on BOTH write (8B halves) and read (16B frags) -> conflict-free.
__global__ __launch_bounds__(256, 3)
void attn_kernel(const unsigned short* __restrict__ Q,
                 const unsigned short* __restrict__ K,
                 const unsigned short* __restrict__ Vt,
                 unsigned short* __restrict__ O)
{
  __shared__ alignas(16) unsigned short Kb[2][64 * 64];   // 16 KB
  __shared__ alignas(16) unsigned short Vb[2][64 * 64];   // 16 KB
  __shared__ alignas(16) unsigned short Pl[4][32][64];    // 16 KB

  const int tid = threadIdx.x;
  const int wv = tid >> 6, lane = tid & 63;
  const int r31 = lane & 31, hi = lane >> 5;

  // XCD-aware decode: 1024 blocks, 128 per XCD chunk -> same-head blocks colocate
  const unsigned flat = blockIdx.x;
  const unsigned wg = (flat & 7) * 128 + (flat >> 3);
  const int qblk = wg & 15;
  const int bh = wg >> 4;

  const size_t hbase = (size_t)bh * (SEQ * HDIM);
  const unsigned short* Qh = Q + hbase;
  const unsigned short* Kh = K + hbase;
  const unsigned short* Vh = Vt + hbase;   // [64][2048]
  const int q0 = qblk * 128 + wv * 32;

  // Q B-frags (n=q=r31, k = kc*16 + hi*8 + j); log2-scaled already
  bf16x8 qf[4];
#pragma unroll
  for (int kc = 0; kc < 4; ++kc)
    qf[kc] = *(const bf16x8*)&Qh[(size_t)(q0 + r31) * HDIM + kc * 16 + hi * 8];

  f32x16 accO[2] = {};
  float m_run = -INFINITY, l_run = 0.0f;

  auto stage = [&](int buf, int kv) {
    const int k0 = kv * 64;
#pragma unroll
    for (int rnd = 0; rnd < 2; ++rnd) {
      const int c = tid + rnd * 256;        // 0..511 chunk id
      const int row = c >> 3, pch = c & 7;
      const int ch = pch ^ (row & 7);       // pre-swizzled source chunk
      gload_lds16(&Kh[(size_t)(k0 + row) * HDIM + ch * 8], &Kb[buf][c * 8]);
      gload_lds16(&Vh[(size_t)row * SEQ + k0 + ch * 8], &Vb[buf][c * 8]);
    }
  };

  stage(0, 0);

  for (int kv = 0; kv < SEQ / 64; ++kv) {
    __syncthreads();                        // tile kv resident
    if (kv + 1 < SEQ / 64) stage((kv + 1) & 1, kv + 1);
    const int buf = kv & 1;

    // ---- QK^T (A=K, B=Q): s0 = keys 0-31, s1 = keys 32-63; col=q=r31 ----
    // C-layout: s*[r] = S[key=(r&3)+8*(r>>2)+4*hi (+32 for s1)][q=r31]
    f32x16 s0 = {}, s1 = {};
#pragma unroll
    for (int kc = 0; kc < 4; ++kc) {
      const int pch = (kc * 2 + hi) ^ (r31 & 7);
      const int base = r31 * 64 + pch * 8;
      const bf16x8 kf0 = *(const bf16x8*)&Kb[buf][base];
      s0 = __builtin_amdgcn_mfma_f32_32x32x16_bf16(kf0, qf[kc], s0, 0, 0, 0);
      const bf16x8 kf1 = *(const bf16x8*)&Kb[buf][base + 2048];
      s1 = __builtin_amdgcn_mfma_f32_32x32x16_bf16(kf1, qf[kc], s1, 0, 0, 0);
    }

    // ---- tile max via max3 trees (log2 units) ----
    float t0 = m3(s0[0], s0[1], s0[2]),   t1 = m3(s0[3], s0[4], s0[5]);
    float t2 = m3(s0[6], s0[7], s0[8]),   t3 = m3(s0[9], s0[10], s0[11]);
    float t4 = m3(s0[12], s0[13], s0[14]);
    float u0 = m3(t0, t1, s0[15]),        u1 = fmaxf(t2, fmaxf(t3, t4));
    float t5 = m3(s1[0], s1[1], s1[2]),   t6 = m3(s1[3], s1[4], s1[5]);
    float t7 = m3(s1[6], s1[7], s1[8]),   t8 = m3(s1[9], s1[10], s1[11]);
    float t9 = m3(s1[12], s1[13], s1[14]);
    float u2 = m3(t5, t6, s1[15]),        u3 = fmaxf(t7, fmaxf(t8, t9));
    float pmax = m3(fmaxf(u0, u1), u2, u3);
    pmax = fmaxf(pmax, __shfl_xor(pmax, 32));

    // ---- defer-max (T13, log2 threshold 8) ----
    if (!__all(pmax - m_run <= 8.0f)) {
      const float mn = fmaxf(m_run, pmax);
      const float al = exp2f(m_run - mn);
      l_run *= al;
#pragma unroll
      for (int f = 0; f < 2; ++f)
#pragma unroll
        for (int r = 0; r < 16; ++r) accO[f][r] *= al;
      m_run = mn;
    }

    // ---- exp2 + packed cvt + swizzled P store; l = unrounded f32 sum ----
    float rs = 0.0f;
    auto dohalf = [&](const f32x16& sv, int f) {
#pragma unroll
      for (int half = 0; half < 4; ++half) {
        const float e0 = exp2f(sv[half * 4 + 0] - m_run);
        const float e1 = exp2f(sv[half * 4 + 1] - m_run);
        const float e2 = exp2f(sv[half * 4 + 2] - m_run);
        const float e3 = exp2f(sv[half * 4 + 3] - m_run);
        rs += (e0 + e1) + (e2 + e3);
        uint2 w; w.x = cvt2(e0, e1); w.y = cvt2(e2, e3);
        // logical 16B chunk c = f*4+half holds keys f*32+half*8+{0..7}; XOR-swizzle by q
        const int pc = (f * 4 + half) ^ (r31 & 7);
        *(uint2*)&Pl[wv][r31][pc * 8 + hi * 4] = w;
      }
    };
    dohalf(s0, 0);
    dohalf(s1, 1);
    rs += __shfl_xor(rs, 32);
    l_run += rs;

    // ---- PV (A=Vt, B=P): O^T[d][q]; P read with same XOR swizzle ----
#pragma unroll
    for (int kc2 = 0; kc2 < 4; ++kc2) {
      const int ppc = (kc2 * 2 + hi) ^ (r31 & 7);
      const bf16x8 pf = *(const bf16x8*)&Pl[wv][r31][ppc * 8];
      const int pch = (kc2 * 2 + hi) ^ (r31 & 7);
      const int vbase = r31 * 64 + pch * 8;
      const bf16x8 vf0 = *(const bf16x8*)&Vb[buf][vbase];
      accO[0] = __builtin_amdgcn_mfma_f32_32x32x16_bf16(vf0, pf, accO[0], 0, 0, 0);
      const bf16x8 vf1 = *(const bf16x8*)&Vb[buf][vbase + 2048];
      accO[1] = __builtin_amdgcn_mfma_f32_32x32x16_bf16(vf1, pf, accO[1], 0, 0, 0);
    }
  }

  // ---- epilogue: O[q][d] = accO^T / l -> [B, S, H*64] bf16 ----
  const int b = bh >> 4, h = bh & 15;
  const float inv = 1.0f / l_run;
  const int qrow = q0 + r31;
  unsigned short* obase = (unsigned short*)&O[((size_t)(b * SEQ + qrow)) * IND + h * HDIM];
#pragma unroll
  for (int f = 0; f < 2; ++f) {
#pragma unroll
    for (int half = 0; half < 4; ++half) {
      // d = 32f + 8*half + 4*hi + {0..3}
      uint2 w;
      w.x = cvt2(accO[f][half * 4 + 0] * inv, accO[f][half * 4 + 1] * inv);
      w.y = cvt2(accO[f][half * 4 + 2] * inv, accO[f][half * 4 + 3] * inv);
      *(uint2*)&obase[32 * f + 8 * half + 4 * hi] = w;
    }
  }
}

// ---------------- launch ----------------
extern "C" void kernel_launch(void* const* d_in, const int* in_sizes, int n_in,
                              void* d_out, int out_size, void* d_ws, size_t ws_size,
                              hipStream_t stream) {
  const float* x  = (const float*)d_in[0];
  const float* Wq = (const float*)d_in[1];
  const float* bq = (const float*)d_in[2];
  const float* Wk = (const float*)d_in[3];
  const float* bk = (const float*)d_in[4];
  const float* Wv = (const float*)d_in[5];
  const float* bv = (const float*)d_in[6];
  const float* Wo = (const float*)d_in[7];
  const float* bo = (const float*)d_in[8];

  char* ws = (char*)d_ws;
  constexpr size_t SZ_XB = (size_t)MTOT * IND * 2;   // 16 MB
  constexpr size_t SZ_W  = (size_t)IND * IND * 2;    // 2 MB
  unsigned short* xb   = (unsigned short*)(ws);
  unsigned short* Wqb  = (unsigned short*)(ws + SZ_XB);
  unsigned short* Wkb  = (unsigned short*)(ws + SZ_XB + SZ_W);
  unsigned short* Wvb  = (unsigned short*)(ws + SZ_XB + 2 * SZ_W);
  unsigned short* Wob  = (unsigned short*)(ws + SZ_XB + 3 * SZ_W);
  unsigned short* Qb   = (unsigned short*)(ws + SZ_XB + 4 * SZ_W);
  unsigned short* Kbuf = (unsigned short*)(ws + 2 * SZ_XB + 4 * SZ_W);
  unsigned short* Vtb  = (unsigned short*)(ws + 3 * SZ_XB + 4 * SZ_W);
  unsigned short* AOb  = (unsigned short*)(ws + 4 * SZ_XB + 4 * SZ_W);

  // fp32 -> bf16 (x + all four weights in 2 launches)
  cvt_kernel<<<2048, 256, 0, stream>>>(x, xb, (MTOT * IND) / 4);
  cvtw_kernel<<<dim3(512, 4), 256, 0, stream>>>(Wq, Wk, Wv, Wo,
                                                Wqb, Wkb, Wvb, Wob, (IND * IND) / 4);

  // QKV projections; Q pre-scaled by log2e/8; V written transposed [B,H,64,S]
  gemm_qkv_kernel<<<dim3(MTOT / 128, IND / 128, 3), 256, 0, stream>>>(
      xb, Wqb, Wkb, Wvb, bq, bk, bv, Qb, Kbuf, Vtb);

  // flash attention: 1024 flat blocks (16 qblk x 64 bh), XCD-swizzled in-kernel
  attn_kernel<<<dim3(16 * BATCH * NHEADS), 256, 0, stream>>>(Qb, Kbuf, Vtb, AOb);

  // output projection -> fp32 d_out
  gemm_o_kernel<<<dim3(MTOT / 128, IND / 128), 256, 0, stream>>>(
      AOb, Wob, bo, (float*)d_out);
}

// Round 9
// 238.257 us; speedup vs baseline: 1.9628x; 1.0268x over previous
//
#include <hip/hip_runtime.h>
#include <hip/hip_bf16.h>
#include <cstdint>
#include <cstddef>

// ---------------- problem constants ----------------
#define NHEADS 16
#define HDIM   64
#define SEQ    2048
#define BATCH  4
#define IND    1024
#define MTOT   (BATCH*SEQ)   // 8192

typedef __attribute__((ext_vector_type(8))) short bf16x8;
typedef __attribute__((ext_vector_type(4))) float f32x4;
typedef __attribute__((ext_vector_type(16))) float f32x16;
typedef __attribute__((ext_vector_type(2))) int i32x2;
typedef __attribute__((ext_vector_type(4))) unsigned u32x4;

__device__ __forceinline__ unsigned short f2b(float f) {
  unsigned u = __builtin_bit_cast(unsigned, f);
  u += 0x7FFFu + ((u >> 16) & 1u);
  return (unsigned short)(u >> 16);
}
// packed 2xf32 -> 2xbf16 RNE via toolchain API (lo -> bits 0-15)
__device__ __forceinline__ unsigned cvt2(float lo, float hi) {
  float2 t; t.x = lo; t.y = hi;
  __hip_bfloat162 h = __float22bfloat162_rn(t);
  const unsigned short ulo = __bfloat16_as_ushort(h.x);
  const unsigned short uhi = __bfloat16_as_ushort(h.y);
  return (unsigned)ulo | ((unsigned)uhi << 16);
}
__device__ __forceinline__ float m3(float a, float b, float c) {
  return fmaxf(fmaxf(a, b), c);   // fuses to v_max3_f32
}

__device__ __forceinline__ void gload_lds16(const void* g, void* l) {
  __builtin_amdgcn_global_load_lds(
      (const __attribute__((address_space(1))) void*)g,
      (__attribute__((address_space(3))) void*)l, 16, 0, 0);
}

// ---------------- fp32 -> bf16 conversion ----------------
__global__ void cvt_kernel(const float* __restrict__ src,
                           unsigned short* __restrict__ dst, int n4) {
  int i = blockIdx.x * blockDim.x + threadIdx.x;
  const int stride = gridDim.x * blockDim.x;
  for (; i < n4; i += stride) {
    const float4 v = reinterpret_cast<const float4*>(src)[i];
    ushort4 o;
    o.x = f2b(v.x); o.y = f2b(v.y); o.z = f2b(v.z); o.w = f2b(v.w);
    reinterpret_cast<ushort4*>(dst)[i] = o;
  }
}

// 4 weight tensors in one launch (blockIdx.y selects)
__global__ void cvtw_kernel(const float* __restrict__ w0, const float* __restrict__ w1,
                            const float* __restrict__ w2, const float* __restrict__ w3,
                            unsigned short* __restrict__ o0, unsigned short* __restrict__ o1,
                            unsigned short* __restrict__ o2, unsigned short* __restrict__ o3,
                            int n4) {
  const int z = blockIdx.y;
  const float* src = (z == 0) ? w0 : (z == 1) ? w1 : (z == 2) ? w2 : w3;
  unsigned short* dst = (z == 0) ? o0 : (z == 1) ? o1 : (z == 2) ? o2 : o3;
  int i = blockIdx.x * blockDim.x + threadIdx.x;
  const int stride = gridDim.x * blockDim.x;
  for (; i < n4; i += stride) {
    const float4 v = reinterpret_cast<const float4*>(src)[i];
    ushort4 o;
    o.x = f2b(v.x); o.y = f2b(v.y); o.z = f2b(v.z); o.w = f2b(v.w);
    reinterpret_cast<ushort4*>(dst)[i] = o;
  }
}

// ---------------- GEMM core: C[m,n] = sum_k A[m,k]*B[n,k] ----------------
// (unchanged verified structure)
template<int EPI>
__device__ __forceinline__ void gemm_core(
    const unsigned short* __restrict__ A,
    const unsigned short* __restrict__ Bw,
    const float* __restrict__ bias,
    void* __restrict__ Cout, float scale)
{
  __shared__ alignas(16) unsigned short As[2][4096];
  __shared__ alignas(16) unsigned short Bs[2][4096];
  const int tid = threadIdx.x;
  const int wv = tid >> 6, lane = tid & 63, g = lane >> 4, li = lane & 15;
  const int wr = (wv >> 1) * 64, wc = (wv & 1) * 64;
  const int m0 = blockIdx.x * 128, n0 = blockIdx.y * 128;

  auto stage = [&](int buf, int kt) {
    const int k0 = kt * 32;
#pragma unroll
    for (int rnd = 0; rnd < 2; ++rnd) {
      const int f = (tid + rnd * 256) * 8;
      const int row = f >> 5, col = f & 31;
      gload_lds16(&A[(size_t)(m0 + row) * IND + k0 + col], &As[buf][f]);
      gload_lds16(&Bw[(size_t)(n0 + row) * IND + k0 + col], &Bs[buf][f]);
    }
  };

  f32x4 acc[4][4] = {};
  stage(0, 0);
  for (int kt = 0; kt < 32; ++kt) {
    __syncthreads();
    if (kt + 1 < 32) stage((kt + 1) & 1, kt + 1);
    const int buf = kt & 1;
    bf16x8 af[4], bfr[4];
#pragma unroll
    for (int i = 0; i < 4; ++i)
      af[i] = *(const bf16x8*)&As[buf][(wr + i * 16 + li) * 32 + g * 8];
#pragma unroll
    for (int i = 0; i < 4; ++i)
      bfr[i] = *(const bf16x8*)&Bs[buf][(wc + i * 16 + li) * 32 + g * 8];
#pragma unroll
    for (int mi = 0; mi < 4; ++mi)
#pragma unroll
      for (int ni = 0; ni < 4; ++ni)
        acc[mi][ni] = __builtin_amdgcn_mfma_f32_16x16x32_bf16(
            af[mi], bfr[ni], acc[mi][ni], 0, 0, 0);
  }

#pragma unroll
  for (int ni = 0; ni < 4; ++ni) {
    const int col = n0 + wc + ni * 16 + li;
    const float bz = bias[col];
#pragma unroll
    for (int mi = 0; mi < 4; ++mi) {
#pragma unroll
      for (int r = 0; r < 4; ++r) {
        const int row = m0 + wr + mi * 16 + g * 4 + r;
        float v = acc[mi][ni][r] + bz;
        if (EPI == 0) {
          v *= scale;
          const int h = col >> 6, d = col & 63;
          const int b = row >> 11, s = row & 2047;
          ((unsigned short*)Cout)[(((size_t)(b * NHEADS + h)) * SEQ + s) * HDIM + d] = f2b(v);
        } else if (EPI == 2) {
          const int h = col >> 6, d = col & 63;
          const int b = row >> 11, s = row & 2047;
          ((unsigned short*)Cout)[(((size_t)(b * NHEADS + h)) * HDIM + d) * SEQ + s] = f2b(v);
        } else {
          ((float*)Cout)[(size_t)row * IND + col] = v;
        }
      }
    }
  }
}

__global__ __launch_bounds__(256, 2)
void gemm_qkv_kernel(const unsigned short* __restrict__ xb,
                     const unsigned short* __restrict__ Wq,
                     const unsigned short* __restrict__ Wk,
                     const unsigned short* __restrict__ Wv,
                     const float* __restrict__ bq,
                     const float* __restrict__ bk,
                     const float* __restrict__ bv,
                     unsigned short* __restrict__ Qo,
                     unsigned short* __restrict__ Ko,
                     unsigned short* __restrict__ Vto)
{
  const int z = blockIdx.z;
  if (z == 2) {
    gemm_core<2>(xb, Wv, bv, Vto, 1.0f);    // V transposed: [B,H,64,S]
  } else {
    const unsigned short* Bw = (z == 0) ? Wq : Wk;
    const float* bias = (z == 0) ? bq : bk;
    unsigned short* out = (z == 0) ? Qo : Ko;
    // Q: fold 1/sqrt(64) AND log2(e) so attention scores are in log2 units
    const float scale = (z == 0) ? 0.18033688011111772f : 1.0f;
    gemm_core<0>(xb, Bw, bias, out, scale);
  }
}

__global__ __launch_bounds__(256, 2)
void gemm_o_kernel(const unsigned short* __restrict__ Ab,
                   const unsigned short* __restrict__ Wo,
                   const float* __restrict__ bo,
                   float* __restrict__ out)
{
  gemm_core<1>(Ab, Wo, bo, out, 1.0f);
}

// ---------------- flash attention: 4 waves x 32 q, KVBLK=64, 32x32x16 MFMA ----------------
// 256 threads; grid flat 1024 = (16 qblk) x (64 bh), XCD-swizzled.
// Scores in log2 units (L2E folded into Q scale).
// K LDS [64 key][64 d], V LDS [64 d][64 key], both chunk-swizzled ch ^= (row&7)
// with pre-swizzled global_load_lds sources (both-sides rule).
// P stays fully in-register: C-layout -> PV B-frags via permlane32_swap:
//   new_vdst[32:63] = old_vsrc[0:31]; new_vsrc[0:31] = old_vdst[32:63].
__global__ __launch_bounds__(256, 4)
void attn_kernel(const unsigned short* __restrict__ Q,
                 const unsigned short* __restrict__ K,
                 const unsigned short* __restrict__ Vt,
                 unsigned short* __restrict__ O)
{
  __shared__ alignas(16) unsigned short Kb[2][64 * 64];   // 16 KB
  __shared__ alignas(16) unsigned short Vb[2][64 * 64];   // 16 KB

  const int tid = threadIdx.x;
  const int wv = tid >> 6, lane = tid & 63;
  const int r31 = lane & 31, hi = lane >> 5;

  // XCD-aware decode: 1024 blocks, 128 per XCD chunk -> same-head blocks colocate
  const unsigned flat = blockIdx.x;
  const unsigned wg = (flat & 7) * 128 + (flat >> 3);
  const int qblk = wg & 15;
  const int bh = wg >> 4;

  const size_t hbase = (size_t)bh * (SEQ * HDIM);
  const unsigned short* Qh = Q + hbase;
  const unsigned short* Kh = K + hbase;
  const unsigned short* Vh = Vt + hbase;   // [64][2048]
  const int q0 = qblk * 128 + wv * 32;

  // Q B-frags (n=q=r31, k = kc*16 + hi*8 + j); log2-scaled already
  bf16x8 qf[4];
#pragma unroll
  for (int kc = 0; kc < 4; ++kc)
    qf[kc] = *(const bf16x8*)&Qh[(size_t)(q0 + r31) * HDIM + kc * 16 + hi * 8];

  f32x16 accO[2] = {};
  float m_run = -INFINITY, l_run = 0.0f;

  auto stage = [&](int buf, int kv) {
    const int k0 = kv * 64;
#pragma unroll
    for (int rnd = 0; rnd < 2; ++rnd) {
      const int c = tid + rnd * 256;        // 0..511 chunk id
      const int row = c >> 3, pch = c & 7;
      const int ch = pch ^ (row & 7);       // pre-swizzled source chunk
      gload_lds16(&Kh[(size_t)(k0 + row) * HDIM + ch * 8], &Kb[buf][c * 8]);
      gload_lds16(&Vh[(size_t)row * SEQ + k0 + ch * 8], &Vb[buf][c * 8]);
    }
  };

  stage(0, 0);

  for (int kv = 0; kv < SEQ / 64; ++kv) {
    __syncthreads();                        // tile kv resident
    if (kv + 1 < SEQ / 64) stage((kv + 1) & 1, kv + 1);
    const int buf = kv & 1;

    // ---- QK^T (A=K, B=Q): s0 = keys 0-31, s1 = keys 32-63; col=q=r31 ----
    // C-layout: s*[r] = S[key=(r&3)+8*(r>>2)+4*hi (+32 for s1)][q=r31]
    f32x16 s0 = {}, s1 = {};
#pragma unroll
    for (int kc = 0; kc < 4; ++kc) {
      const int pch = (kc * 2 + hi) ^ (r31 & 7);
      const int base = r31 * 64 + pch * 8;
      const bf16x8 kf0 = *(const bf16x8*)&Kb[buf][base];
      s0 = __builtin_amdgcn_mfma_f32_32x32x16_bf16(kf0, qf[kc], s0, 0, 0, 0);
      const bf16x8 kf1 = *(const bf16x8*)&Kb[buf][base + 2048];
      s1 = __builtin_amdgcn_mfma_f32_32x32x16_bf16(kf1, qf[kc], s1, 0, 0, 0);
    }

    // ---- tile max via max3 trees (log2 units) ----
    float t0 = m3(s0[0], s0[1], s0[2]),   t1 = m3(s0[3], s0[4], s0[5]);
    float t2 = m3(s0[6], s0[7], s0[8]),   t3 = m3(s0[9], s0[10], s0[11]);
    float t4 = m3(s0[12], s0[13], s0[14]);
    float u0 = m3(t0, t1, s0[15]),        u1 = fmaxf(t2, fmaxf(t3, t4));
    float t5 = m3(s1[0], s1[1], s1[2]),   t6 = m3(s1[3], s1[4], s1[5]);
    float t7 = m3(s1[6], s1[7], s1[8]),   t8 = m3(s1[9], s1[10], s1[11]);
    float t9 = m3(s1[12], s1[13], s1[14]);
    float u2 = m3(t5, t6, s1[15]),        u3 = fmaxf(t7, fmaxf(t8, t9));
    float pmax = m3(fmaxf(u0, u1), u2, u3);
    pmax = fmaxf(pmax, __shfl_xor(pmax, 32));

    // ---- defer-max (T13, log2 threshold 8) ----
    if (!__all(pmax - m_run <= 8.0f)) {
      const float mn = fmaxf(m_run, pmax);
      const float al = exp2f(m_run - mn);
      l_run *= al;
#pragma unroll
      for (int f = 0; f < 2; ++f)
#pragma unroll
        for (int r = 0; r < 16; ++r) accO[f][r] *= al;
      m_run = mn;
    }

    // ---- exp2 + pack adjacent C-reg pairs; l = unrounded f32 sum ----
    // pk[i] (i<8 from s0, i>=8 from s1): keys {k(2i), k(2i+1)} for q=r31
    unsigned pk[16];
    float rs = 0.0f;
#pragma unroll
    for (int i = 0; i < 8; ++i) {
      const float ea = exp2f(s0[2 * i] - m_run);
      const float eb = exp2f(s0[2 * i + 1] - m_run);
      rs += ea + eb;
      pk[i] = cvt2(ea, eb);
    }
#pragma unroll
    for (int i = 0; i < 8; ++i) {
      const float ea = exp2f(s1[2 * i] - m_run);
      const float eb = exp2f(s1[2 * i + 1] - m_run);
      rs += ea + eb;
      pk[8 + i] = cvt2(ea, eb);
    }
    rs += __shfl_xor(rs, 32);
    l_run += rs;

    // ---- C-layout -> PV B-frags via permlane32_swap ----
    // swap(vdst=pk[b], vsrc=pk[b+2]) -> ret[0]=new_vdst=w(j01), ret[1]=new_vsrc=w(j45):
    //   new_vdst: lo lanes keep own low keys, hi lanes receive lo-half's mid keys;
    //   new_vsrc: lo lanes receive hi-half's keys, hi lanes keep own high keys.
    bf16x8 pf[4];
#pragma unroll
    for (int kc2 = 0; kc2 < 4; ++kc2) {
      const int bs = kc2 * 4;
      const i32x2 rA = __builtin_amdgcn_permlane32_swap(
          (int)pk[bs + 0], (int)pk[bs + 2], false, false);
      const i32x2 rB = __builtin_amdgcn_permlane32_swap(
          (int)pk[bs + 1], (int)pk[bs + 3], false, false);
      u32x4 u;
      u[0] = (unsigned)rA[0];   // w0 = elements j=0,1
      u[1] = (unsigned)rB[0];   // w1 = elements j=2,3
      u[2] = (unsigned)rA[1];   // w2 = elements j=4,5
      u[3] = (unsigned)rB[1];   // w3 = elements j=6,7
      pf[kc2] = __builtin_bit_cast(bf16x8, u);
    }

    // ---- PV (A=Vt, B=P): O^T[d][q] ----
#pragma unroll
    for (int kc2 = 0; kc2 < 4; ++kc2) {
      const int pch = (kc2 * 2 + hi) ^ (r31 & 7);
      const int vbase = r31 * 64 + pch * 8;
      const bf16x8 vf0 = *(const bf16x8*)&Vb[buf][vbase];
      accO[0] = __builtin_amdgcn_mfma_f32_32x32x16_bf16(vf0, pf[kc2], accO[0], 0, 0, 0);
      const bf16x8 vf1 = *(const bf16x8*)&Vb[buf][vbase + 2048];
      accO[1] = __builtin_amdgcn_mfma_f32_32x32x16_bf16(vf1, pf[kc2], accO[1], 0, 0, 0);
    }
  }

  // ---- epilogue: O[q][d] = accO^T / l -> [B, S, H*64] bf16 ----
  const int b = bh >> 4, h = bh & 15;
  const float inv = 1.0f / l_run;
  const int qrow = q0 + r31;
  unsigned short* obase = (unsigned short*)&O[((size_t)(b * SEQ + qrow)) * IND + h * HDIM];
#pragma unroll
  for (int f = 0; f < 2; ++f) {
#pragma unroll
    for (int half = 0; half < 4; ++half) {
      // d = 32f + 8*half + 4*hi + {0..3}
      uint2 w;
      w.x = cvt2(accO[f][half * 4 + 0] * inv, accO[f][half * 4 + 1] * inv);
      w.y = cvt2(accO[f][half * 4 + 2] * inv, accO[f][half * 4 + 3] * inv);
      *(uint2*)&obase[32 * f + 8 * half + 4 * hi] = w;
    }
  }
}

// ---------------- launch ----------------
extern "C" void kernel_launch(void* const* d_in, const int* in_sizes, int n_in,
                              void* d_out, int out_size, void* d_ws, size_t ws_size,
                              hipStream_t stream) {
  const float* x  = (const float*)d_in[0];
  const float* Wq = (const float*)d_in[1];
  const float* bq = (const float*)d_in[2];
  const float* Wk = (const float*)d_in[3];
  const float* bk = (const float*)d_in[4];
  const float* Wv = (const float*)d_in[5];
  const float* bv = (const float*)d_in[6];
  const float* Wo = (const float*)d_in[7];
  const float* bo = (const float*)d_in[8];

  char* ws = (char*)d_ws;
  constexpr size_t SZ_XB = (size_t)MTOT * IND * 2;   // 16 MB
  constexpr size_t SZ_W  = (size_t)IND * IND * 2;    // 2 MB
  unsigned short* xb   = (unsigned short*)(ws);
  unsigned short* Wqb  = (unsigned short*)(ws + SZ_XB);
  unsigned short* Wkb  = (unsigned short*)(ws + SZ_XB + SZ_W);
  unsigned short* Wvb  = (unsigned short*)(ws + SZ_XB + 2 * SZ_W);
  unsigned short* Wob  = (unsigned short*)(ws + SZ_XB + 3 * SZ_W);
  unsigned short* Qb   = (unsigned short*)(ws + SZ_XB + 4 * SZ_W);
  unsigned short* Kbuf = (unsigned short*)(ws + 2 * SZ_XB + 4 * SZ_W);
  unsigned short* Vtb  = (unsigned short*)(ws + 3 * SZ_XB + 4 * SZ_W);
  unsigned short* AOb  = (unsigned short*)(ws + 4 * SZ_XB + 4 * SZ_W);

  // fp32 -> bf16 (x + all four weights in 2 launches)
  cvt_kernel<<<2048, 256, 0, stream>>>(x, xb, (MTOT * IND) / 4);
  cvtw_kernel<<<dim3(512, 4), 256, 0, stream>>>(Wq, Wk, Wv, Wo,
                                                Wqb, Wkb, Wvb, Wob, (IND * IND) / 4);

  // QKV projections; Q pre-scaled by log2e/8; V written transposed [B,H,64,S]
  gemm_qkv_kernel<<<dim3(MTOT / 128, IND / 128, 3), 256, 0, stream>>>(
      xb, Wqb, Wkb, Wvb, bq, bk, bv, Qb, Kbuf, Vtb);

  // flash attention: 1024 flat blocks (16 qblk x 64 bh), XCD-swizzled in-kernel
  attn_kernel<<<dim3(16 * BATCH * NHEADS), 256, 0, stream>>>(Qb, Kbuf, Vtb, AOb);

  // output projection -> fp32 d_out
  gemm_o_kernel<<<dim3(MTOT / 128, IND / 128), 256, 0, stream>>>(
      AOb, Wob, bo, (float*)d_out);
}

// Round 10
// 207.330 us; speedup vs baseline: 2.2556x; 1.1492x over previous
//
#include <hip/hip_runtime.h>
#include <hip/hip_bf16.h>
#include <cstdint>
#include <cstddef>

// ---------------- problem constants ----------------
#define NHEADS 16
#define HDIM   64
#define SEQ    2048
#define BATCH  4
#define IND    1024
#define MTOT   (BATCH*SEQ)   // 8192

typedef __attribute__((ext_vector_type(8))) short bf16x8;
typedef __attribute__((ext_vector_type(8))) _Float16 f16x8;
typedef __attribute__((ext_vector_type(2))) _Float16 f16x2;
typedef __attribute__((ext_vector_type(4))) float f32x4;
typedef __attribute__((ext_vector_type(16))) float f32x16;
typedef __attribute__((ext_vector_type(2))) int i32x2;
typedef __attribute__((ext_vector_type(4))) unsigned u32x4;

#if __has_builtin(__builtin_amdgcn_exp2f)
#define EXP2(x) __builtin_amdgcn_exp2f(x)
#else
#define EXP2(x) exp2f(x)
#endif

__device__ __forceinline__ unsigned short f2b(float f) {
  unsigned u = __builtin_bit_cast(unsigned, f);
  u += 0x7FFFu + ((u >> 16) & 1u);
  return (unsigned short)(u >> 16);
}
// packed 2xf32 -> 2xbf16 RNE via toolchain API (lo -> bits 0-15)
__device__ __forceinline__ unsigned cvt2(float lo, float hi) {
  float2 t; t.x = lo; t.y = hi;
  __hip_bfloat162 h = __float22bfloat162_rn(t);
  const unsigned short ulo = __bfloat16_as_ushort(h.x);
  const unsigned short uhi = __bfloat16_as_ushort(h.y);
  return (unsigned)ulo | ((unsigned)uhi << 16);
}
__device__ __forceinline__ float m3(float a, float b, float c) {
  return fmaxf(fmaxf(a, b), c);   // fuses to v_max3_f32
}

__device__ __forceinline__ void gload_lds16(const void* g, void* l) {
  __builtin_amdgcn_global_load_lds(
      (const __attribute__((address_space(1))) void*)g,
      (__attribute__((address_space(3))) void*)l, 16, 0, 0);
}

// ---------------- fp32 -> bf16 conversion ----------------
__global__ void cvt_kernel(const float* __restrict__ src,
                           unsigned short* __restrict__ dst, int n4) {
  int i = blockIdx.x * blockDim.x + threadIdx.x;
  const int stride = gridDim.x * blockDim.x;
  for (; i < n4; i += stride) {
    const float4 v = reinterpret_cast<const float4*>(src)[i];
    ushort4 o;
    o.x = f2b(v.x); o.y = f2b(v.y); o.z = f2b(v.z); o.w = f2b(v.w);
    reinterpret_cast<ushort4*>(dst)[i] = o;
  }
}

// 4 weight tensors in one launch (blockIdx.y selects)
__global__ void cvtw_kernel(const float* __restrict__ w0, const float* __restrict__ w1,
                            const float* __restrict__ w2, const float* __restrict__ w3,
                            unsigned short* __restrict__ o0, unsigned short* __restrict__ o1,
                            unsigned short* __restrict__ o2, unsigned short* __restrict__ o3,
                            int n4) {
  const int z = blockIdx.y;
  const float* src = (z == 0) ? w0 : (z == 1) ? w1 : (z == 2) ? w2 : w3;
  unsigned short* dst = (z == 0) ? o0 : (z == 1) ? o1 : (z == 2) ? o2 : o3;
  int i = blockIdx.x * blockDim.x + threadIdx.x;
  const int stride = gridDim.x * blockDim.x;
  for (; i < n4; i += stride) {
    const float4 v = reinterpret_cast<const float4*>(src)[i];
    ushort4 o;
    o.x = f2b(v.x); o.y = f2b(v.y); o.z = f2b(v.z); o.w = f2b(v.w);
    reinterpret_cast<ushort4*>(dst)[i] = o;
  }
}

// ---------------- GEMM core: C[m,n] = sum_k A[m,k]*B[n,k] ----------------
// EPI==0: bf16 out to [B,H,S,64], value=(acc+bias)*scale
// EPI==2: FP16 out to [B,H,64,S] (transposed, for attention V)
// EPI==1: f32 out row-major [M,1024]
template<int EPI>
__device__ __forceinline__ void gemm_core(
    const unsigned short* __restrict__ A,
    const unsigned short* __restrict__ Bw,
    const float* __restrict__ bias,
    void* __restrict__ Cout, float scale)
{
  __shared__ alignas(16) unsigned short As[2][4096];
  __shared__ alignas(16) unsigned short Bs[2][4096];
  const int tid = threadIdx.x;
  const int wv = tid >> 6, lane = tid & 63, g = lane >> 4, li = lane & 15;
  const int wr = (wv >> 1) * 64, wc = (wv & 1) * 64;
  const int m0 = blockIdx.x * 128, n0 = blockIdx.y * 128;

  auto stage = [&](int buf, int kt) {
    const int k0 = kt * 32;
#pragma unroll
    for (int rnd = 0; rnd < 2; ++rnd) {
      const int f = (tid + rnd * 256) * 8;
      const int row = f >> 5, col = f & 31;
      gload_lds16(&A[(size_t)(m0 + row) * IND + k0 + col], &As[buf][f]);
      gload_lds16(&Bw[(size_t)(n0 + row) * IND + k0 + col], &Bs[buf][f]);
    }
  };

  f32x4 acc[4][4] = {};
  stage(0, 0);
  for (int kt = 0; kt < 32; ++kt) {
    __syncthreads();
    if (kt + 1 < 32) stage((kt + 1) & 1, kt + 1);
    const int buf = kt & 1;
    bf16x8 af[4], bfr[4];
#pragma unroll
    for (int i = 0; i < 4; ++i)
      af[i] = *(const bf16x8*)&As[buf][(wr + i * 16 + li) * 32 + g * 8];
#pragma unroll
    for (int i = 0; i < 4; ++i)
      bfr[i] = *(const bf16x8*)&Bs[buf][(wc + i * 16 + li) * 32 + g * 8];
#pragma unroll
    for (int mi = 0; mi < 4; ++mi)
#pragma unroll
      for (int ni = 0; ni < 4; ++ni)
        acc[mi][ni] = __builtin_amdgcn_mfma_f32_16x16x32_bf16(
            af[mi], bfr[ni], acc[mi][ni], 0, 0, 0);
  }

#pragma unroll
  for (int ni = 0; ni < 4; ++ni) {
    const int col = n0 + wc + ni * 16 + li;
    const float bz = bias[col];
#pragma unroll
    for (int mi = 0; mi < 4; ++mi) {
#pragma unroll
      for (int r = 0; r < 4; ++r) {
        const int row = m0 + wr + mi * 16 + g * 4 + r;
        float v = acc[mi][ni][r] + bz;
        if (EPI == 0) {
          v *= scale;
          const int h = col >> 6, d = col & 63;
          const int b = row >> 11, s = row & 2047;
          ((unsigned short*)Cout)[(((size_t)(b * NHEADS + h)) * SEQ + s) * HDIM + d] = f2b(v);
        } else if (EPI == 2) {
          const int h = col >> 6, d = col & 63;
          const int b = row >> 11, s = row & 2047;
          ((_Float16*)Cout)[(((size_t)(b * NHEADS + h)) * HDIM + d) * SEQ + s] = (_Float16)v;
        } else {
          ((float*)Cout)[(size_t)row * IND + col] = v;
        }
      }
    }
  }
}

__global__ __launch_bounds__(256, 2)
void gemm_qkv_kernel(const unsigned short* __restrict__ xb,
                     const unsigned short* __restrict__ Wq,
                     const unsigned short* __restrict__ Wk,
                     const unsigned short* __restrict__ Wv,
                     const float* __restrict__ bq,
                     const float* __restrict__ bk,
                     const float* __restrict__ bv,
                     unsigned short* __restrict__ Qo,
                     unsigned short* __restrict__ Ko,
                     unsigned short* __restrict__ Vto)
{
  const int z = blockIdx.z;
  if (z == 2) {
    gemm_core<2>(xb, Wv, bv, Vto, 1.0f);    // V transposed fp16: [B,H,64,S]
  } else {
    const unsigned short* Bw = (z == 0) ? Wq : Wk;
    const float* bias = (z == 0) ? bq : bk;
    unsigned short* out = (z == 0) ? Qo : Ko;
    // Q: fold 1/sqrt(64) AND log2(e) so attention scores are in log2 units
    const float scale = (z == 0) ? 0.18033688011111772f : 1.0f;
    gemm_core<0>(xb, Bw, bias, out, scale);
  }
}

__global__ __launch_bounds__(256, 2)
void gemm_o_kernel(const unsigned short* __restrict__ Ab,
                   const unsigned short* __restrict__ Wo,
                   const float* __restrict__ bo,
                   float* __restrict__ out)
{
  gemm_core<1>(Ab, Wo, bo, out, 1.0f);
}

// ---------------- flash attention: 4 waves x 32 q, KVBLK=64 ----------------
// QK^T bf16 (A=K, B=Q, 32x32x16); PV fp16 (A=Vt f16, B=P f16).
// P in-register via cvt_pkrtz + permlane32_swap (verified r9).
// l via ones-row MFMA: accL = mfma(onesA, P) accumulates row-sums; l = accL[0].
__global__ __launch_bounds__(256, 4)
void attn_kernel(const unsigned short* __restrict__ Q,
                 const unsigned short* __restrict__ K,
                 const unsigned short* __restrict__ Vt,
                 unsigned short* __restrict__ O)
{
  __shared__ alignas(16) unsigned short Kb[2][64 * 64];   // 16 KB
  __shared__ alignas(16) unsigned short Vb[2][64 * 64];   // 16 KB (f16 payload)

  const int tid = threadIdx.x;
  const int wv = tid >> 6, lane = tid & 63;
  const int r31 = lane & 31, hi = lane >> 5;

  // XCD-aware decode: 1024 blocks, 128 per XCD chunk -> same-head blocks colocate
  const unsigned flat = blockIdx.x;
  const unsigned wg = (flat & 7) * 128 + (flat >> 3);
  const int qblk = wg & 15;
  const int bh = wg >> 4;

  const size_t hbase = (size_t)bh * (SEQ * HDIM);
  const unsigned short* Qh = Q + hbase;
  const unsigned short* Kh = K + hbase;
  const unsigned short* Vh = Vt + hbase;   // f16 [64][2048]
  const int q0 = qblk * 128 + wv * 32;

  // Q B-frags (n=q=r31, k = kc*16 + hi*8 + j); log2-scaled already
  bf16x8 qf[4];
#pragma unroll
  for (int kc = 0; kc < 4; ++kc)
    qf[kc] = *(const bf16x8*)&Qh[(size_t)(q0 + r31) * HDIM + kc * 16 + hi * 8];

  // ones A-frag for l: row 0 = 1.0, rows 1-31 = 0  (row = r31)
  f16x8 onesA;
  {
    const _Float16 ov = (r31 == 0) ? (_Float16)1.0f : (_Float16)0.0f;
#pragma unroll
    for (int j = 0; j < 8; ++j) onesA[j] = ov;
  }

  f32x16 accO[2] = {};
  f32x16 accL = {};
  float m_run = -INFINITY;

  auto stage = [&](int buf, int kv) {
    const int k0 = kv * 64;
#pragma unroll
    for (int rnd = 0; rnd < 2; ++rnd) {
      const int c = tid + rnd * 256;        // 0..511 chunk id
      const int row = c >> 3, pch = c & 7;
      const int ch = pch ^ (row & 7);       // pre-swizzled source chunk
      gload_lds16(&Kh[(size_t)(k0 + row) * HDIM + ch * 8], &Kb[buf][c * 8]);
      gload_lds16(&Vh[(size_t)row * SEQ + k0 + ch * 8], &Vb[buf][c * 8]);
    }
  };

  stage(0, 0);

  for (int kv = 0; kv < SEQ / 64; ++kv) {
    __syncthreads();                        // tile kv resident
    if (kv + 1 < SEQ / 64) stage((kv + 1) & 1, kv + 1);
    const int buf = kv & 1;

    // ---- QK^T (A=K, B=Q): s0 = keys 0-31, s1 = keys 32-63; col=q=r31 ----
    // C-layout: s*[r] = S[key=(r&3)+8*(r>>2)+4*hi (+32 for s1)][q=r31]
    f32x16 s0 = {}, s1 = {};
#pragma unroll
    for (int kc = 0; kc < 4; ++kc) {
      const int pch = (kc * 2 + hi) ^ (r31 & 7);
      const int base = r31 * 64 + pch * 8;
      const bf16x8 kf0 = *(const bf16x8*)&Kb[buf][base];
      s0 = __builtin_amdgcn_mfma_f32_32x32x16_bf16(kf0, qf[kc], s0, 0, 0, 0);
      const bf16x8 kf1 = *(const bf16x8*)&Kb[buf][base + 2048];
      s1 = __builtin_amdgcn_mfma_f32_32x32x16_bf16(kf1, qf[kc], s1, 0, 0, 0);
    }

    // ---- tile max via max3 trees (log2 units) ----
    float t0 = m3(s0[0], s0[1], s0[2]),   t1 = m3(s0[3], s0[4], s0[5]);
    float t2 = m3(s0[6], s0[7], s0[8]),   t3 = m3(s0[9], s0[10], s0[11]);
    float t4 = m3(s0[12], s0[13], s0[14]);
    float u0 = m3(t0, t1, s0[15]),        u1 = fmaxf(t2, fmaxf(t3, t4));
    float t5 = m3(s1[0], s1[1], s1[2]),   t6 = m3(s1[3], s1[4], s1[5]);
    float t7 = m3(s1[6], s1[7], s1[8]),   t8 = m3(s1[9], s1[10], s1[11]);
    float t9 = m3(s1[12], s1[13], s1[14]);
    float u2 = m3(t5, t6, s1[15]),        u3 = fmaxf(t7, fmaxf(t8, t9));
    float pmax = m3(fmaxf(u0, u1), u2, u3);
    pmax = fmaxf(pmax, __shfl_xor(pmax, 32));

    // ---- defer-max (T13, log2 threshold 8) ----
    if (!__all(pmax - m_run <= 8.0f)) {
      const float mn = fmaxf(m_run, pmax);
      const float al = EXP2(m_run - mn);
#pragma unroll
      for (int f = 0; f < 2; ++f)
#pragma unroll
        for (int r = 0; r < 16; ++r) accO[f][r] *= al;
      accL[0] *= al;
      m_run = mn;
    }

    // ---- exp2 + pack adjacent C-reg pairs to fp16 (pkrtz builtin: lo=S0) ----
    // pk[i] (i<8 from s0, i>=8 from s1): keys {k(2i), k(2i+1)} for q=r31
    unsigned pk[16];
#pragma unroll
    for (int i = 0; i < 8; ++i) {
      const float ea = EXP2(s0[2 * i] - m_run);
      const float eb = EXP2(s0[2 * i + 1] - m_run);
      pk[i] = __builtin_bit_cast(unsigned, __builtin_amdgcn_cvt_pkrtz(ea, eb));
    }
#pragma unroll
    for (int i = 0; i < 8; ++i) {
      const float ea = EXP2(s1[2 * i] - m_run);
      const float eb = EXP2(s1[2 * i + 1] - m_run);
      pk[8 + i] = __builtin_bit_cast(unsigned, __builtin_amdgcn_cvt_pkrtz(ea, eb));
    }

    // ---- C-layout -> PV B-frags via permlane32_swap (verified r9) ----
    f16x8 pf[4];
#pragma unroll
    for (int kc2 = 0; kc2 < 4; ++kc2) {
      const int bs = kc2 * 4;
      const i32x2 rA = __builtin_amdgcn_permlane32_swap(
          (int)pk[bs + 0], (int)pk[bs + 2], false, false);
      const i32x2 rB = __builtin_amdgcn_permlane32_swap(
          (int)pk[bs + 1], (int)pk[bs + 3], false, false);
      u32x4 u;
      u[0] = (unsigned)rA[0];   // w0 = elements j=0,1
      u[1] = (unsigned)rB[0];   // w1 = elements j=2,3
      u[2] = (unsigned)rA[1];   // w2 = elements j=4,5
      u[3] = (unsigned)rB[1];   // w3 = elements j=6,7
      pf[kc2] = __builtin_bit_cast(f16x8, u);
    }

    // ---- PV (A=Vt f16, B=P f16): O^T[d][q]; l-row via onesA ----
#pragma unroll
    for (int kc2 = 0; kc2 < 4; ++kc2) {
      const int pch = (kc2 * 2 + hi) ^ (r31 & 7);
      const int vbase = r31 * 64 + pch * 8;
      const f16x8 vf0 = *(const f16x8*)&Vb[buf][vbase];
      accO[0] = __builtin_amdgcn_mfma_f32_32x32x16_f16(vf0, pf[kc2], accO[0], 0, 0, 0);
      const f16x8 vf1 = *(const f16x8*)&Vb[buf][vbase + 2048];
      accO[1] = __builtin_amdgcn_mfma_f32_32x32x16_f16(vf1, pf[kc2], accO[1], 0, 0, 0);
      accL = __builtin_amdgcn_mfma_f32_32x32x16_f16(onesA, pf[kc2], accL, 0, 0, 0);
    }
  }

  // ---- l = accL[0] (row 0, held by hi=0 lanes; hi=1 lanes hold 0) ----
  float lv = accL[0];
  lv += __shfl_xor(lv, 32);

  // ---- epilogue: O[q][d] = accO^T / l -> [B, S, H*64] bf16 ----
  const int b = bh >> 4, h = bh & 15;
  const float inv = 1.0f / lv;
  const int qrow = q0 + r31;
  unsigned short* obase = (unsigned short*)&O[((size_t)(b * SEQ + qrow)) * IND + h * HDIM];
#pragma unroll
  for (int f = 0; f < 2; ++f) {
#pragma unroll
    for (int half = 0; half < 4; ++half) {
      // d = 32f + 8*half + 4*hi + {0..3}
      uint2 w;
      w.x = cvt2(accO[f][half * 4 + 0] * inv, accO[f][half * 4 + 1] * inv);
      w.y = cvt2(accO[f][half * 4 + 2] * inv, accO[f][half * 4 + 3] * inv);
      *(uint2*)&obase[32 * f + 8 * half + 4 * hi] = w;
    }
  }
}

// ---------------- launch ----------------
extern "C" void kernel_launch(void* const* d_in, const int* in_sizes, int n_in,
                              void* d_out, int out_size, void* d_ws, size_t ws_size,
                              hipStream_t stream) {
  const float* x  = (const float*)d_in[0];
  const float* Wq = (const float*)d_in[1];
  const float* bq = (const float*)d_in[2];
  const float* Wk = (const float*)d_in[3];
  const float* bk = (const float*)d_in[4];
  const float* Wv = (const float*)d_in[5];
  const float* bv = (const float*)d_in[6];
  const float* Wo = (const float*)d_in[7];
  const float* bo = (const float*)d_in[8];

  char* ws = (char*)d_ws;
  constexpr size_t SZ_XB = (size_t)MTOT * IND * 2;   // 16 MB
  constexpr size_t SZ_W  = (size_t)IND * IND * 2;    // 2 MB
  unsigned short* xb   = (unsigned short*)(ws);
  unsigned short* Wqb  = (unsigned short*)(ws + SZ_XB);
  unsigned short* Wkb  = (unsigned short*)(ws + SZ_XB + SZ_W);
  unsigned short* Wvb  = (unsigned short*)(ws + SZ_XB + 2 * SZ_W);
  unsigned short* Wob  = (unsigned short*)(ws + SZ_XB + 3 * SZ_W);
  unsigned short* Qb   = (unsigned short*)(ws + SZ_XB + 4 * SZ_W);
  unsigned short* Kbuf = (unsigned short*)(ws + 2 * SZ_XB + 4 * SZ_W);
  unsigned short* Vtb  = (unsigned short*)(ws + 3 * SZ_XB + 4 * SZ_W);
  unsigned short* AOb  = (unsigned short*)(ws + 4 * SZ_XB + 4 * SZ_W);

  // fp32 -> bf16 (x + all four weights in 2 launches)
  cvt_kernel<<<2048, 256, 0, stream>>>(x, xb, (MTOT * IND) / 4);
  cvtw_kernel<<<dim3(512, 4), 256, 0, stream>>>(Wq, Wk, Wv, Wo,
                                                Wqb, Wkb, Wvb, Wob, (IND * IND) / 4);

  // QKV projections; Q pre-scaled by log2e/8; V written transposed fp16 [B,H,64,S]
  gemm_qkv_kernel<<<dim3(MTOT / 128, IND / 128, 3), 256, 0, stream>>>(
      xb, Wqb, Wkb, Wvb, bq, bk, bv, Qb, Kbuf, Vtb);

  // flash attention: 1024 flat blocks (16 qblk x 64 bh), XCD-swizzled in-kernel
  attn_kernel<<<dim3(16 * BATCH * NHEADS), 256, 0, stream>>>(Qb, Kbuf, Vtb, AOb);

  // output projection -> fp32 d_out
  gemm_o_kernel<<<dim3(MTOT / 128, IND / 128), 256, 0, stream>>>(
      AOb, Wob, bo, (float*)d_out);
}